// Round 15
// baseline (1062.447 us; speedup 1.0000x reference)
//
#include <hip/hip_runtime.h>
#include <stdint.h>

#define B_ 4
#define S_ 2048
#define D_ 1024
#define H_ 16
#define A_ 64
#define LN_EPS 1e-3f

typedef __bf16 bf16x8 __attribute__((ext_vector_type(8)));
typedef __bf16 bf16x4 __attribute__((ext_vector_type(4)));
typedef float f32x4 __attribute__((ext_vector_type(4)));

__device__ __forceinline__ f32x4 mfma16(bf16x8 a, bf16x8 b, f32x4 c) {
    return __builtin_amdgcn_mfma_f32_16x16x32_bf16(a, b, c, 0, 0, 0);
}
__device__ __forceinline__ void glds16(const void* g, void* l) {
    __builtin_amdgcn_global_load_lds(
        (const __attribute__((address_space(1))) void*)g,
        (__attribute__((address_space(3))) void*)l, 16, 0, 0);
}

// ---- swizzled [128][64] half-tile staging ----
#define SWZ(slot, r) ((slot) ^ (((r) & 1) << 2) ^ (((r) >> 1) & 3))
__device__ __forceinline__ void stage_half(const __bf16* __restrict__ src, size_t ld,
                                           __bf16* lhalf, int w, int lane) {
    #pragma unroll
    for (int i = 0; i < 2; ++i) {
        int ch = w * 2 + i;
        int r = ch * 8 + (lane >> 3);
        int sl = SWZ(lane & 7, r);
        glds16(src + (size_t)r * ld + sl * 8, lhalf + ch * 512);
    }
}
__device__ __forceinline__ bf16x8 fragS(const __bf16* h, int r, int ks, int fg) {
    return *(const bf16x8*)(h + r * 64 + SWZ(ks * 4 + fg, r) * 8);
}

// ---- linear [128][32] tile staging (proj 2-phase core), 4 waves ----
__device__ __forceinline__ void glds_tile128(const __bf16* __restrict__ src, size_t ld,
                                             __bf16* lds, int w, int lane) {
    int r = lane >> 2;
    int c = (lane & 3) * 8;
    #pragma unroll
    for (int i = 0; i < 2; ++i) {
        int r0 = (w + i * 4) * 16;
        glds16(src + (size_t)(r0 + r) * ld + c, lds + r0 * 32);
    }
}
template <int NI, int NJ>
__device__ __forceinline__ void mfma_tileL(const __bf16* As, const __bf16* Bs,
                                           int wm, int wn, int fr, int fg,
                                           f32x4 (&acc)[NI][NJ]) {
    bf16x8 af[NI], bv[NJ];
    #pragma unroll
    for (int i = 0; i < NI; ++i)
        af[i] = *(const bf16x8*)(As + (wm + i * 16 + fr) * 32 + fg * 8);
    #pragma unroll
    for (int j = 0; j < NJ; ++j)
        bv[j] = *(const bf16x8*)(Bs + (wn + j * 16 + fr) * 32 + fg * 8);
    #pragma unroll
    for (int i = 0; i < NI; ++i)
        #pragma unroll
        for (int j = 0; j < NJ; ++j)
            acc[i][j] = mfma16(af[i], bv[j], acc[i][j]);
}

// ---------------- tiled transpose + f32->bf16 convert ----------------
__global__ void k_tr_cvt(const float* __restrict__ in, __bf16* __restrict__ out,
                         int R, int C) {
    __shared__ float tile[32][33];
    size_t gbase = (size_t)blockIdx.z * R * C;
    int r0 = blockIdx.y * 32, c0 = blockIdx.x * 32;
    #pragma unroll
    for (int i = threadIdx.y; i < 32; i += 8)
        tile[i][threadIdx.x] = in[gbase + (size_t)(r0 + i) * C + c0 + threadIdx.x];
    __syncthreads();
    #pragma unroll
    for (int i = threadIdx.y; i < 32; i += 8)
        out[gbase + (size_t)(c0 + i) * R + r0 + threadIdx.x] = (__bf16)tile[threadIdx.x][i];
}
__global__ void k_tr_cvt2(const float* __restrict__ in0, const float* __restrict__ in1,
                          __bf16* __restrict__ out0, __bf16* __restrict__ out1,
                          int R, int C) {
    __shared__ float tile[32][33];
    int z = blockIdx.z;
    const float* in = (z < H_) ? in0 : in1;
    __bf16* out = (z < H_) ? out0 : out1;
    size_t gbase = (size_t)(z & (H_ - 1)) * R * C;
    int r0 = blockIdx.y * 32, c0 = blockIdx.x * 32;
    #pragma unroll
    for (int i = threadIdx.y; i < 32; i += 8)
        tile[i][threadIdx.x] = in[gbase + (size_t)(r0 + i) * C + c0 + threadIdx.x];
    __syncthreads();
    #pragma unroll
    for (int i = threadIdx.y; i < 32; i += 8)
        out[gbase + (size_t)(c0 + i) * R + r0 + threadIdx.x] = (__bf16)tile[threadIdx.x][i];
}

// ---------------- Q/K projection: f32 A reg-staged (fused convert) x bf16 W^T glds ----------------
// q pre-scaled by (1/sqrt(A)) * log2(e) so fattn can use exp2 directly.
__global__ __launch_bounds__(256) void k_proj(
    const float* __restrict__ qin, const float* __restrict__ kvin,
    const __bf16* __restrict__ wqt, const __bf16* __restrict__ wkt,
    const float* __restrict__ bq, const float* __restrict__ bk,
    __bf16* __restrict__ qp, __bf16* __restrict__ kp) {
    __shared__ __bf16 As[2][128 * 32];
    __shared__ __bf16 Bs[2][128 * 32];
    int which = blockIdx.z;
    const float* Af = which ? kvin : qin;
    const __bf16* Bt = which ? wkt : wqt;
    const float* bias = which ? bk : bq;
    float scale = which ? 1.0f : 0.18033688011112042f;  // 0.125 * log2(e)
    __bf16* outp = which ? kp : qp;
    int m0 = blockIdx.y * 128, n0 = blockIdx.x * 128;
    int t = threadIdx.x, lane = t & 63, w = t >> 6;
    int wm = (w >> 1) * 64, wn = (w & 1) * 64;
    int fr = lane & 15, fg = lane >> 4;
    const float* Abase = Af + (size_t)m0 * D_;
    const __bf16* Bbase = Bt + (size_t)n0 * D_;
    uint4 areg[2];
    auto loadA = [&](int k0) {
        #pragma unroll
        for (int i = 0; i < 2; ++i) {
            int id = t + i * 256, row = id >> 2, ch = (id & 3) * 8;
            const float* p = Abase + (size_t)row * D_ + k0 + ch;
            float4 f0 = *(const float4*)p;
            float4 f1 = *(const float4*)(p + 4);
            __bf16 v8[8] = {(__bf16)f0.x, (__bf16)f0.y, (__bf16)f0.z, (__bf16)f0.w,
                            (__bf16)f1.x, (__bf16)f1.y, (__bf16)f1.z, (__bf16)f1.w};
            areg[i] = *(const uint4*)v8;
        }
    };
    auto writeA = [&](__bf16* dst) {
        #pragma unroll
        for (int i = 0; i < 2; ++i) {
            int id = t + i * 256, row = id >> 2, ch = (id & 3) * 8;
            *(uint4*)(dst + row * 32 + ch) = areg[i];
        }
    };
    f32x4 acc[4][4] = {};
    loadA(0);
    glds_tile128(Bbase, D_, Bs[0], w, lane);
    writeA(As[0]);
    __syncthreads();
    int cur = 0;
    const int nt = D_ / 32;
    for (int tt = 0; tt < nt; ++tt) {
        if (tt + 1 < nt) {
            loadA((tt + 1) * 32);
            glds_tile128(Bbase + (tt + 1) * 32, D_, Bs[cur ^ 1], w, lane);
        }
        mfma_tileL<4, 4>(As[cur], Bs[cur], wm, wn, fr, fg, acc);
        if (tt + 1 < nt) writeA(As[cur ^ 1]);
        __syncthreads();
        cur ^= 1;
    }
    #pragma unroll
    for (int j = 0; j < 4; ++j) {
        int n = n0 + wn + j * 16 + fr;
        float bv = bias[n];
        #pragma unroll
        for (int i = 0; i < 4; ++i)
            #pragma unroll
            for (int jj = 0; jj < 4; ++jj) {
                int m = m0 + wm + i * 16 + fg * 4 + jj;
                outp[(size_t)m * (H_ * A_) + n] = (__bf16)((acc[i][j][jj] + bv) * scale);
            }
    }
}

// ---------------- fused flash attention, BN=512, K glds-dbuf, pure-PV phase B ----------------
// Ledger: post-A(t)-barrier issue V(t+1)x8 then K(t+1)x1. At A(t+1): vmcnt(0)
// drains both (K last-issued) — one full tile of cover for each. Phase B is pure
// compute. Ks[(t+1)&1] write-safe: its last reader QK(t-1) drained at the
// P~-barrier(t-1) lgkm(0). lpar aliases Ps (post-loop lgkm+barrier before writes).
__global__ __launch_bounds__(512, 1) void k_fattn(
    const __bf16* __restrict__ qpb, const __bf16* __restrict__ kpb,
    const __bf16* __restrict__ kvtb, __bf16* __restrict__ att) {
    __shared__ __bf16 Ks[2][64 * 64];       // 16 KB double-buffered
    __shared__ __bf16 Vs[2][4][128 * 64];   // 128 KB
    __shared__ __bf16 Ps[128 * 64];         // 16 KB (Q staging + P~ + lpar alias)
    float (*lpar)[2] = (float(*)[2])Ps;     // aliased: used only after last PV
    int bid = blockIdx.x;                   // 256 blocks
    int xcd = bid & 7, slot = bid >> 3;     // slot 0..31
    int n0 = (xcd & 1) * 512;
    int h = (xcd >> 1) * 4 + (slot >> 3);
    int yp = slot & 7;
    int t = threadIdx.x, lane = t & 63, w = t >> 6;
    int fr = lane & 15, fg = lane >> 4;
    int wr = w >> 2, wc = w & 3;   // PV: rows wr*64, cols wc*128
    int sr = w >> 1, sc = w & 1;   // QK^T: rows sr*32, cols sc*32
    const __bf16* Vb = kvtb + (size_t)n0 * S_;
    __bf16* ob = att + (size_t)h * S_ * D_;
    int kr = w * 8 + (lane >> 3);       // K stage row (64 rows over 8 waves)
    int ksl = SWZ(lane & 7, kr);        // K stage source slot

    #pragma unroll 1
    for (int seg = 0; seg < 2; ++seg) {
        int mt = seg ? (15 - yp) : yp;
        int m0 = mt * 128;
        int NT = (mt + 1) * 2;
        // ---- prologue: Q -> Ps -> regs; K(0) glds; V(0) glds ----
        stage_half(qpb + (size_t)m0 * (H_ * A_) + h * A_, H_ * A_, Ps, w, lane);
        glds16(kpb + (size_t)kr * (H_ * A_) + h * A_ + ksl * 8, &Ks[0][w * 512]);
        asm volatile("s_waitcnt vmcnt(0)" ::: "memory");
        __builtin_amdgcn_s_barrier();
        bf16x8 qf[2][2];
        #pragma unroll
        for (int mi = 0; mi < 2; ++mi)
            #pragma unroll
            for (int ks = 0; ks < 2; ++ks)
                qf[mi][ks] = fragS(Ps, sr * 32 + mi * 16 + fr, ks, fg);
        asm volatile("s_waitcnt lgkmcnt(0)" ::: "memory");
        #pragma unroll
        for (int q = 0; q < 4; ++q)
            stage_half(Vb + (size_t)(q * 128) * S_, S_, &Vs[0][q][0], w, lane);
        __builtin_amdgcn_s_barrier();  // Q reads done before P~ writes
        __builtin_amdgcn_sched_barrier(0);
        f32x4 acc[4][8] = {};
        float lsum[2][4] = {};
        int cur = 0;
        for (int tt = 0; tt < NT; ++tt) {
            bool pre = (tt + 1 < NT);
            // ---- phase A: drain V(t)+K(t); issue V(t+1)+K(t+1); QK^T + exp + P~ ----
            asm volatile("s_waitcnt vmcnt(0)" ::: "memory");
            asm volatile("s_waitcnt lgkmcnt(0)" ::: "memory");
            __builtin_amdgcn_s_barrier();
            __builtin_amdgcn_sched_barrier(0);
            if (pre) {
                #pragma unroll
                for (int q = 0; q < 4; ++q)
                    stage_half(Vb + (size_t)(q * 128) * S_ + (tt + 1) * 64, S_,
                               &Vs[cur ^ 1][q][0], w, lane);
                glds16(kpb + (size_t)((tt + 1) * 64 + kr) * (H_ * A_) + h * A_ + ksl * 8,
                       &Ks[(tt + 1) & 1][w * 512]);
            }
            f32x4 sac[2][2] = {};
            __builtin_amdgcn_s_setprio(1);
            #pragma unroll
            for (int ks = 0; ks < 2; ++ks)
                #pragma unroll
                for (int nj = 0; nj < 2; ++nj) {
                    bf16x8 kf = fragS(&Ks[tt & 1][0], sc * 32 + nj * 16 + fr, ks, fg);
                    #pragma unroll
                    for (int mi = 0; mi < 2; ++mi)
                        sac[mi][nj] = mfma16(qf[mi][ks], kf, sac[mi][nj]);
                }
            __builtin_amdgcn_s_setprio(0);
            bool dg = (tt >= 2 * mt);   // block-uniform: only last 2 tiles touch diagonal
            if (dg) {
                #pragma unroll
                for (int mi = 0; mi < 2; ++mi)
                    #pragma unroll
                    for (int nj = 0; nj < 2; ++nj)
                        #pragma unroll
                        for (int jj = 0; jj < 4; ++jj) {
                            int srow = sr * 32 + mi * 16 + fg * 4 + jj;
                            int col = sc * 32 + nj * 16 + fr;
                            float p = exp2f(sac[mi][nj][jj]);
                            if (tt * 64 + col > m0 + srow) p = 0.f;
                            lsum[mi][jj] += p;
                            Ps[srow * 64 + (col ^ (fg << 4))] = (__bf16)p;
                        }
            } else {
                #pragma unroll
                for (int mi = 0; mi < 2; ++mi)
                    #pragma unroll
                    for (int nj = 0; nj < 2; ++nj)
                        #pragma unroll
                        for (int jj = 0; jj < 4; ++jj) {
                            int srow = sr * 32 + mi * 16 + fg * 4 + jj;
                            int col = sc * 32 + nj * 16 + fr;
                            float p = exp2f(sac[mi][nj][jj]);
                            lsum[mi][jj] += p;
                            Ps[srow * 64 + (col ^ (fg << 4))] = (__bf16)p;
                        }
            }
            asm volatile("s_waitcnt lgkmcnt(0)" ::: "memory");
            __builtin_amdgcn_s_barrier();
            __builtin_amdgcn_sched_barrier(0);
            // ---- phase B: pure PV ----
            __builtin_amdgcn_s_setprio(1);
            const __bf16* Vh = &Vs[cur][wc][0];
            #pragma unroll
            for (int ks = 0; ks < 2; ++ks) {
                bf16x8 pa[4], vf[8];
                #pragma unroll
                for (int mi = 0; mi < 4; ++mi) {
                    int r = wr * 64 + mi * 16 + fr;
                    int g = (ks * 4 + fg) ^ (((fr >> 2) & 3) << 1);
                    pa[mi] = *(const bf16x8*)(Ps + r * 64 + g * 8);
                }
                #pragma unroll
                for (int nj = 0; nj < 8; ++nj)
                    vf[nj] = fragS(Vh, nj * 16 + fr, ks, fg);
                #pragma unroll
                for (int mi = 0; mi < 4; ++mi)
                    #pragma unroll
                    for (int nj = 0; nj < 8; ++nj)
                        acc[mi][nj] = mfma16(pa[mi], vf[nj], acc[mi][nj]);
            }
            __builtin_amdgcn_s_setprio(0);
            __builtin_amdgcn_sched_barrier(0);
            cur ^= 1;
        }
        // ---- all PV reads of Ps done before lpar (aliased) writes ----
        asm volatile("s_waitcnt lgkmcnt(0)" ::: "memory");
        __builtin_amdgcn_s_barrier();
        // ---- row sums: shfl over fr, combine the 2 col-waves via LDS ----
        #pragma unroll
        for (int mi = 0; mi < 2; ++mi)
            #pragma unroll
            for (int jj = 0; jj < 4; ++jj) {
                float v = lsum[mi][jj];
                v += __shfl_xor(v, 1);
                v += __shfl_xor(v, 2);
                v += __shfl_xor(v, 4);
                v += __shfl_xor(v, 8);
                if (fr == 0) lpar[sr * 32 + mi * 16 + fg * 4 + jj][sc] = v;
            }
        asm volatile("s_waitcnt lgkmcnt(0)" ::: "memory");
        __builtin_amdgcn_s_barrier();
        // ---- epilogue: normalize + store ----
        #pragma unroll
        for (int mi = 0; mi < 4; ++mi)
            #pragma unroll
            for (int jj = 0; jj < 4; ++jj) {
                int row = wr * 64 + mi * 16 + fg * 4 + jj;
                float il = 1.f / (lpar[row][0] + lpar[row][1]);
                int m = m0 + row;
                #pragma unroll
                for (int nj = 0; nj < 8; ++nj) {
                    int n = n0 + wc * 128 + nj * 16 + fr;
                    ob[(size_t)m * D_ + n] = (__bf16)(acc[mi][nj][jj] * il);
                }
            }
        __builtin_amdgcn_s_barrier();  // Ps/lpar/Ks reuse across segs
    }
}

// ---------------- per-head Wo GEMM + bias + relu -> bf16 partials, 256^2 8-phase ----------------
__global__ __launch_bounds__(512) void k_headsum(
    const __bf16* __restrict__ att, const __bf16* __restrict__ Wot,
    const float* __restrict__ bo, __bf16* __restrict__ asum) {
    __shared__ __bf16 L[2][4][8192];
    int bid = blockIdx.x;                    // 512 blocks
    int xcd = bid & 7, slot = bid >> 3;      // slot 0..63
    int p = xcd * 2 + (slot >> 5);           // head 0..15
    int rem = slot & 31;
    int mt = rem >> 2;                       // 0..7
    int n0 = (rem & 3) * 256;
    int m0 = mt * 256;
    int t = threadIdx.x, lane = t & 63, w = t >> 6;
    int wr = w >> 2, wc = w & 3;
    int fr = lane & 15, fg = lane >> 4;
    const __bf16* Ab = att + ((size_t)p * S_ + m0) * D_;
    const __bf16* Bb = Wot + ((size_t)p * D_ + n0) * D_;
    float bv4[4];
    #pragma unroll
    for (int j = 0; j < 4; ++j)
        bv4[j] = bo[(size_t)p * D_ + n0 + wc * 64 + j * 16 + fr];
    f32x4 acc[8][4] = {};
    auto stg = [&](int tt, int h, int buf) {
        const __bf16* s = (h < 2) ? (Ab + (size_t)(h * 128) * D_ + tt * 64)
                                  : (Bb + (size_t)((h - 2) * 128) * D_ + tt * 64);
        stage_half(s, D_, &L[buf][h][0], w, lane);
    };
    auto loads = [&](const __bf16* Ah, const __bf16* Bh, int rb0, int mh, int nh,
                     bf16x8 (&af)[4][2], bf16x8 (&bv)[2][2]) {
        #pragma unroll
        for (int i = 0; i < 4; ++i)
            #pragma unroll
            for (int ks = 0; ks < 2; ++ks)
                af[i][ks] = fragS(Ah, mh * 64 + i * 16 + fr, ks, fg);
        #pragma unroll
        for (int j = 0; j < 2; ++j)
            #pragma unroll
            for (int ks = 0; ks < 2; ++ks)
                bv[j][ks] = fragS(Bh, rb0 + nh * 32 + j * 16 + fr, ks, fg);
    };
    stg(0, 0, 0); stg(0, 1, 0); stg(0, 2, 0); stg(0, 3, 0);
    int cur = 0;
    const int nt = D_ / 64;
    for (int tt = 0; tt < nt; ++tt) {
        bool pre = (tt + 1 < nt);
        const __bf16* Ah = &L[cur][wr][0];
        const __bf16* Bh = &L[cur][2 + (wc >> 1)][0];
        int rb0 = (wc & 1) * 64;
        #pragma unroll
        for (int ph = 0; ph < 4; ++ph) {
            const int mh = ph >> 1, nh = ph & 1;
            bf16x8 af[4][2], bv[2][2];
            if (ph == 0) {
                if (pre) {
                    stg(tt + 1, 0, cur ^ 1);
                    stg(tt + 1, 1, cur ^ 1);
                    stg(tt + 1, 2, cur ^ 1);
                    stg(tt + 1, 3, cur ^ 1);
                    asm volatile("s_waitcnt vmcnt(8)" ::: "memory");
                } else {
                    asm volatile("s_waitcnt vmcnt(0)" ::: "memory");
                }
                __builtin_amdgcn_s_barrier();
                __builtin_amdgcn_sched_barrier(0);
                loads(Ah, Bh, rb0, mh, nh, af, bv);
            } else {
                loads(Ah, Bh, rb0, mh, nh, af, bv);
                __builtin_amdgcn_s_barrier();
                __builtin_amdgcn_sched_barrier(0);
            }
            __builtin_amdgcn_s_setprio(1);
            #pragma unroll
            for (int i = 0; i < 4; ++i)
                #pragma unroll
                for (int j = 0; j < 2; ++j) {
                    acc[mh * 4 + i][nh * 2 + j] =
                        mfma16(af[i][0], bv[j][0], acc[mh * 4 + i][nh * 2 + j]);
                    acc[mh * 4 + i][nh * 2 + j] =
                        mfma16(af[i][1], bv[j][1], acc[mh * 4 + i][nh * 2 + j]);
                }
            __builtin_amdgcn_s_setprio(0);
            __builtin_amdgcn_sched_barrier(0);
            __builtin_amdgcn_s_barrier();
        }
        cur ^= 1;
    }
    __bf16* dst = asum + ((size_t)p * S_ + m0) * D_;
    #pragma unroll
    for (int mi = 0; mi < 8; ++mi)
        #pragma unroll
        for (int jj = 0; jj < 4; ++jj) {
            int mr = wr * 128 + mi * 16 + fg * 4 + jj;
            #pragma unroll
            for (int nj = 0; nj < 4; ++nj) {
                int nc = n0 + wc * 64 + nj * 16 + fr;
                dst[(size_t)mr * D_ + nc] = (__bf16)fmaxf(acc[mi][nj][jj] + bv4[nj], 0.f);
            }
        }
}

// ---------------- residual + 16-partial bf16 sum + LayerNorm (per batch) ----------------
__global__ __launch_bounds__(256) void k_ln(
    const float* __restrict__ x1b, const __bf16* __restrict__ parts,
    const float* __restrict__ gamma, const float* __restrict__ beta,
    float* __restrict__ outb) {
    int row = blockIdx.x;
    size_t base = (size_t)row * D_;
    int c = threadIdx.x * 4;
    float4 a = *(const float4*)(x1b + base + c);
    float x[4] = {a.x, a.y, a.z, a.w};
    #pragma unroll
    for (int p = 0; p < H_; ++p) {
        bf16x4 v = *(const bf16x4*)(parts + ((size_t)p * S_ + row) * D_ + c);
        x[0] += (float)v[0]; x[1] += (float)v[1];
        x[2] += (float)v[2]; x[3] += (float)v[3];
    }
    float sm = x[0] + x[1] + x[2] + x[3];
    float s2 = x[0] * x[0] + x[1] * x[1] + x[2] * x[2] + x[3] * x[3];
    #pragma unroll
    for (int m = 32; m >= 1; m >>= 1) {
        sm += __shfl_xor(sm, m);
        s2 += __shfl_xor(s2, m);
    }
    __shared__ float r1[4], r2[4];
    int w = threadIdx.x >> 6;
    if ((threadIdx.x & 63) == 0) { r1[w] = sm; r2[w] = s2; }
    __syncthreads();
    sm = r1[0] + r1[1] + r1[2] + r1[3];
    s2 = r2[0] + r2[1] + r2[2] + r2[3];
    float mean = sm * (1.f / D_);
    float var = s2 * (1.f / D_) - mean * mean;
    float rstd = rsqrtf(var + LN_EPS);
    #pragma unroll
    for (int jj = 0; jj < 4; ++jj)
        outb[base + c + jj] = gamma[c + jj] * (x[jj] - mean) * rstd + beta[c + jj];
}

// ---------------- host ----------------
extern "C" void kernel_launch(void* const* d_in, const int* in_sizes, int n_in,
                              void* d_out, int out_size, void* d_ws, size_t ws_size,
                              hipStream_t stream) {
    (void)in_sizes; (void)n_in; (void)out_size; (void)ws_size;
    const float* qin   = (const float*)d_in[0];
    const float* kvin  = (const float*)d_in[1];
    const float* Wq    = (const float*)d_in[2];
    const float* bq    = (const float*)d_in[3];
    const float* Wk    = (const float*)d_in[4];
    const float* bk    = (const float*)d_in[5];
    const float* Wo    = (const float*)d_in[6];
    const float* bo    = (const float*)d_in[7];
    const float* gamma = (const float*)d_in[8];
    const float* beta  = (const float*)d_in[9];
    float* out = (float*)d_out;
    char* ws = (char*)d_ws;

    size_t off = 0;
    auto alloc = [&](size_t bytes) {
        size_t o = off;
        off += (bytes + 255) & ~(size_t)255;
        return o;
    };
    size_t o_wqt = alloc((size_t)H_ * A_ * D_ * 2);
    size_t o_wkt = alloc((size_t)H_ * A_ * D_ * 2);
    size_t o_wot = alloc((size_t)H_ * D_ * D_ * 2);
    size_t o_kvt = alloc((size_t)B_ * D_ * S_ * 2);
    size_t o_qp  = alloc((size_t)B_ * S_ * H_ * A_ * 2);
    size_t o_kp  = alloc((size_t)B_ * S_ * H_ * A_ * 2);
    size_t o_att = alloc((size_t)H_ * S_ * D_ * 2);
    size_t o_as  = alloc((size_t)H_ * S_ * D_ * 2);   // asum bf16 (per batch)

    __bf16* wqt = (__bf16*)(ws + o_wqt);
    __bf16* wkt = (__bf16*)(ws + o_wkt);
    __bf16* wot = (__bf16*)(ws + o_wot);
    __bf16* kvt = (__bf16*)(ws + o_kvt);
    __bf16* qp  = (__bf16*)(ws + o_qp);
    __bf16* kp  = (__bf16*)(ws + o_kp);
    __bf16* att = (__bf16*)(ws + o_att);
    __bf16* asum = (__bf16*)(ws + o_as);

    k_tr_cvt2<<<dim3(A_ / 32, D_ / 32, 2 * H_), dim3(32, 8), 0, stream>>>(
        Wq, Wk, wqt, wkt, D_, A_);
    k_tr_cvt<<<dim3(D_ / 32, D_ / 32, H_), dim3(32, 8), 0, stream>>>(Wo, wot, D_, D_);
    k_tr_cvt<<<dim3(D_ / 32, S_ / 32, B_), dim3(32, 8), 0, stream>>>(kvin, kvt, S_, D_);
    // projections: f32 inputs, conversion fused (A reg-staged)
    k_proj<<<dim3(8, 64, 2), 256, 0, stream>>>(qin, kvin, wqt, wkt, bq, bk, qp, kp);

    for (int b = 0; b < B_; ++b) {
        const __bf16* qpb  = qp + (size_t)b * S_ * (H_ * A_);
        const __bf16* kpb  = kp + (size_t)b * S_ * (H_ * A_);
        const __bf16* kvtb = kvt + (size_t)b * D_ * S_;
        k_fattn<<<256, 512, 0, stream>>>(qpb, kpb, kvtb, att);
        k_headsum<<<512, 512, 0, stream>>>(att, wot, bo, asum);
        k_ln<<<S_, 256, 0, stream>>>(qin + (size_t)b * S_ * D_, asum, gamma, beta,
                                     out + (size_t)b * S_ * D_);
    }
}

// Round 16
// 1011.256 us; speedup vs baseline: 1.0506x; 1.0506x over previous
//
#include <hip/hip_runtime.h>
#include <stdint.h>

#define B_ 4
#define S_ 2048
#define D_ 1024
#define H_ 16
#define A_ 64
#define LN_EPS 1e-3f

typedef __bf16 bf16x8 __attribute__((ext_vector_type(8)));
typedef __bf16 bf16x4 __attribute__((ext_vector_type(4)));
typedef float f32x4 __attribute__((ext_vector_type(4)));

__device__ __forceinline__ f32x4 mfma16(bf16x8 a, bf16x8 b, f32x4 c) {
    return __builtin_amdgcn_mfma_f32_16x16x32_bf16(a, b, c, 0, 0, 0);
}
__device__ __forceinline__ void glds16(const void* g, void* l) {
    __builtin_amdgcn_global_load_lds(
        (const __attribute__((address_space(1))) void*)g,
        (__attribute__((address_space(3))) void*)l, 16, 0, 0);
}

// ---- swizzled [128][64] half-tile staging ----
#define SWZ(slot, r) ((slot) ^ (((r) & 1) << 2) ^ (((r) >> 1) & 3))
__device__ __forceinline__ void stage_half(const __bf16* __restrict__ src, size_t ld,
                                           __bf16* lhalf, int w, int lane) {
    #pragma unroll
    for (int i = 0; i < 2; ++i) {
        int ch = w * 2 + i;
        int r = ch * 8 + (lane >> 3);
        int sl = SWZ(lane & 7, r);
        glds16(src + (size_t)r * ld + sl * 8, lhalf + ch * 512);
    }
}
__device__ __forceinline__ bf16x8 fragS(const __bf16* h, int r, int ks, int fg) {
    return *(const bf16x8*)(h + r * 64 + SWZ(ks * 4 + fg, r) * 8);
}

// ---- linear [128][32] tile staging (proj 2-phase core), 4 waves ----
__device__ __forceinline__ void glds_tile128(const __bf16* __restrict__ src, size_t ld,
                                             __bf16* lds, int w, int lane) {
    int r = lane >> 2;
    int c = (lane & 3) * 8;
    #pragma unroll
    for (int i = 0; i < 2; ++i) {
        int r0 = (w + i * 4) * 16;
        glds16(src + (size_t)(r0 + r) * ld + c, lds + r0 * 32);
    }
}
template <int NI, int NJ>
__device__ __forceinline__ void mfma_tileL(const __bf16* As, const __bf16* Bs,
                                           int wm, int wn, int fr, int fg,
                                           f32x4 (&acc)[NI][NJ]) {
    bf16x8 af[NI], bv[NJ];
    #pragma unroll
    for (int i = 0; i < NI; ++i)
        af[i] = *(const bf16x8*)(As + (wm + i * 16 + fr) * 32 + fg * 8);
    #pragma unroll
    for (int j = 0; j < NJ; ++j)
        bv[j] = *(const bf16x8*)(Bs + (wn + j * 16 + fr) * 32 + fg * 8);
    #pragma unroll
    for (int i = 0; i < NI; ++i)
        #pragma unroll
        for (int j = 0; j < NJ; ++j)
            acc[i][j] = mfma16(af[i], bv[j], acc[i][j]);
}

// ---------------- tiled transpose + f32->bf16 convert ----------------
__global__ void k_tr_cvt(const float* __restrict__ in, __bf16* __restrict__ out,
                         int R, int C) {
    __shared__ float tile[32][33];
    size_t gbase = (size_t)blockIdx.z * R * C;
    int r0 = blockIdx.y * 32, c0 = blockIdx.x * 32;
    #pragma unroll
    for (int i = threadIdx.y; i < 32; i += 8)
        tile[i][threadIdx.x] = in[gbase + (size_t)(r0 + i) * C + c0 + threadIdx.x];
    __syncthreads();
    #pragma unroll
    for (int i = threadIdx.y; i < 32; i += 8)
        out[gbase + (size_t)(c0 + i) * R + r0 + threadIdx.x] = (__bf16)tile[threadIdx.x][i];
}
__global__ void k_tr_cvt2(const float* __restrict__ in0, const float* __restrict__ in1,
                          __bf16* __restrict__ out0, __bf16* __restrict__ out1,
                          int R, int C) {
    __shared__ float tile[32][33];
    int z = blockIdx.z;
    const float* in = (z < H_) ? in0 : in1;
    __bf16* out = (z < H_) ? out0 : out1;
    size_t gbase = (size_t)(z & (H_ - 1)) * R * C;
    int r0 = blockIdx.y * 32, c0 = blockIdx.x * 32;
    #pragma unroll
    for (int i = threadIdx.y; i < 32; i += 8)
        tile[i][threadIdx.x] = in[gbase + (size_t)(r0 + i) * C + c0 + threadIdx.x];
    __syncthreads();
    #pragma unroll
    for (int i = threadIdx.y; i < 32; i += 8)
        out[gbase + (size_t)(c0 + i) * R + r0 + threadIdx.x] = (__bf16)tile[threadIdx.x][i];
}

// ---------------- kv prep: one read of kvin -> kvt (transposed) + kvb (linear) ----------------
__global__ void k_kv_prep(const float* __restrict__ in, __bf16* __restrict__ outT,
                          __bf16* __restrict__ outL) {
    __shared__ float tile[32][33];
    size_t gbase = (size_t)blockIdx.z * S_ * D_;
    int r0 = blockIdx.y * 32, c0 = blockIdx.x * 32;
    #pragma unroll
    for (int i = threadIdx.y; i < 32; i += 8) {
        float v = in[gbase + (size_t)(r0 + i) * D_ + c0 + threadIdx.x];
        tile[i][threadIdx.x] = v;
        outL[gbase + (size_t)(r0 + i) * D_ + c0 + threadIdx.x] = (__bf16)v;
    }
    __syncthreads();
    #pragma unroll
    for (int i = threadIdx.y; i < 32; i += 8)
        outT[gbase + (size_t)(c0 + i) * S_ + r0 + threadIdx.x] = (__bf16)tile[threadIdx.x][i];
}

// ---------------- elementwise f32 -> bf16 ----------------
__global__ void k_cvt(const float* __restrict__ in, __bf16* __restrict__ out, int n8) {
    int i = blockIdx.x * blockDim.x + threadIdx.x;
    if (i >= n8) return;
    const float4* p = (const float4*)(in + (size_t)i * 8);
    float4 f0 = p[0], f1 = p[1];
    __bf16 v[8] = {(__bf16)f0.x, (__bf16)f0.y, (__bf16)f0.z, (__bf16)f0.w,
                   (__bf16)f1.x, (__bf16)f1.y, (__bf16)f1.z, (__bf16)f1.w};
    *(uint4*)(out + (size_t)i * 8) = *(const uint4*)v;
}

// ---------------- Q/K projection: bf16 glds 2-phase dbuf, both in one dispatch ----------------
// q pre-scaled by (1/sqrt(A)) * log2(e) so fattn can use exp2 directly.
__global__ __launch_bounds__(256) void k_proj(
    const __bf16* __restrict__ qb, const __bf16* __restrict__ kvb,
    const __bf16* __restrict__ wqt, const __bf16* __restrict__ wkt,
    const float* __restrict__ bq, const float* __restrict__ bk,
    __bf16* __restrict__ qp, __bf16* __restrict__ kp) {
    __shared__ __bf16 As[2][128 * 32];
    __shared__ __bf16 Bs[2][128 * 32];
    int which = blockIdx.z;
    const __bf16* Ab = which ? kvb : qb;
    const __bf16* Bt = which ? wkt : wqt;
    const float* bias = which ? bk : bq;
    float scale = which ? 1.0f : 0.18033688011112042f;  // 0.125 * log2(e)
    __bf16* outp = which ? kp : qp;
    int m0 = blockIdx.y * 128, n0 = blockIdx.x * 128;
    int t = threadIdx.x, lane = t & 63, w = t >> 6;
    int wm = (w >> 1) * 64, wn = (w & 1) * 64;
    int fr = lane & 15, fg = lane >> 4;
    const __bf16* Abase = Ab + (size_t)m0 * D_;
    const __bf16* Bbase = Bt + (size_t)n0 * D_;
    f32x4 acc[4][4] = {};
    glds_tile128(Abase, D_, As[0], w, lane);
    glds_tile128(Bbase, D_, Bs[0], w, lane);
    __syncthreads();
    int cur = 0;
    const int nt = D_ / 32;
    for (int tt = 0; tt < nt; ++tt) {
        if (tt + 1 < nt) {
            glds_tile128(Abase + (tt + 1) * 32, D_, As[cur ^ 1], w, lane);
            glds_tile128(Bbase + (tt + 1) * 32, D_, Bs[cur ^ 1], w, lane);
        }
        mfma_tileL<4, 4>(As[cur], Bs[cur], wm, wn, fr, fg, acc);
        __syncthreads();
        cur ^= 1;
    }
    #pragma unroll
    for (int j = 0; j < 4; ++j) {
        int n = n0 + wn + j * 16 + fr;
        float bv = bias[n];
        #pragma unroll
        for (int i = 0; i < 4; ++i)
            #pragma unroll
            for (int jj = 0; jj < 4; ++jj) {
                int m = m0 + wm + i * 16 + fg * 4 + jj;
                outp[(size_t)m * (H_ * A_) + n] = (__bf16)((acc[i][j][jj] + bv) * scale);
            }
    }
}

// ---------------- fused flash attention, BN=512, XCD-local, full-tile V cover ----------------
// R14-exact structure (measured best: 129.7 us/dispatch). Only delta: exp2f(sac)
// directly — the L2E factor is folded into the Q projection scale.
// Ledger: A(t) entry [V(t)x8, kreg(t+1)] -> vmcnt(1) drains V(t); post-barrier
// issue V(t+1); B(t) vmcnt(8) drains kreg(t+1); Ks<-kreg; load kreg(t+2).
__global__ __launch_bounds__(512, 1) void k_fattn(
    const __bf16* __restrict__ qpb, const __bf16* __restrict__ kpb,
    const __bf16* __restrict__ kvtb, __bf16* __restrict__ att) {
    __shared__ __bf16 Ks[64 * 64];          // 8 KB, single buffer
    __shared__ __bf16 Vs[2][4][128 * 64];   // 128 KB
    __shared__ __bf16 Ps[128 * 64];         // 16 KB (also Q staging)
    __shared__ float lpar[128][2];          // 1 KB
    int bid = blockIdx.x;                   // 256 blocks
    int xcd = bid & 7, slot = bid >> 3;     // slot 0..31
    int n0 = (xcd & 1) * 512;
    int h = (xcd >> 1) * 4 + (slot >> 3);
    int yp = slot & 7;
    int t = threadIdx.x, lane = t & 63, w = t >> 6;
    int fr = lane & 15, fg = lane >> 4;
    int wr = w >> 2, wc = w & 3;   // PV: rows wr*64, cols wc*128
    int sr = w >> 1, sc = w & 1;   // QK^T: rows sr*32, cols sc*32
    const __bf16* Vb = kvtb + (size_t)n0 * S_;
    __bf16* ob = att + (size_t)h * S_ * D_;
    int kr = w * 8 + (lane >> 3);       // K stage row (64 rows over 8 waves)
    int ksl = SWZ(lane & 7, kr);        // K stage source slot

    #pragma unroll 1
    for (int seg = 0; seg < 2; ++seg) {
        int mt = seg ? (15 - yp) : yp;
        int m0 = mt * 128;
        int NT = (mt + 1) * 2;
        // ---- prologue: Q -> Ps -> regs; K0 glds; V0 glds; K1 -> reg ----
        stage_half(qpb + (size_t)m0 * (H_ * A_) + h * A_, H_ * A_, Ps, w, lane);
        glds16(kpb + (size_t)kr * (H_ * A_) + h * A_ + ksl * 8, Ks + w * 512);
        asm volatile("s_waitcnt vmcnt(0)" ::: "memory");
        __builtin_amdgcn_s_barrier();
        bf16x8 qf[2][2];
        #pragma unroll
        for (int mi = 0; mi < 2; ++mi)
            #pragma unroll
            for (int ks = 0; ks < 2; ++ks)
                qf[mi][ks] = fragS(Ps, sr * 32 + mi * 16 + fr, ks, fg);
        asm volatile("s_waitcnt lgkmcnt(0)" ::: "memory");
        #pragma unroll
        for (int q = 0; q < 4; ++q)
            stage_half(Vb + (size_t)(q * 128) * S_, S_, &Vs[0][q][0], w, lane);
        uint4 kreg = {0, 0, 0, 0};
        if (NT > 1)
            kreg = *(const uint4*)(kpb + (size_t)(64 + kr) * (H_ * A_) + h * A_ + ksl * 8);
        __builtin_amdgcn_s_barrier();  // Q reads done before P~ writes
        __builtin_amdgcn_sched_barrier(0);
        f32x4 acc[4][8] = {};
        float lsum[2][4] = {};
        int cur = 0;
        for (int tt = 0; tt < NT; ++tt) {
            bool pre = (tt + 1 < NT);
            // ---- phase A: wait V(t); issue V(t+1) post-barrier; QK^T + exp + P~ ----
            if (pre) {
                asm volatile("s_waitcnt vmcnt(1)" ::: "memory");   // drain V(t)x8
            } else {
                asm volatile("s_waitcnt vmcnt(0)" ::: "memory");
            }
            asm volatile("s_waitcnt lgkmcnt(0)" ::: "memory");
            __builtin_amdgcn_s_barrier();
            __builtin_amdgcn_sched_barrier(0);
            if (pre) {
                #pragma unroll
                for (int q = 0; q < 4; ++q)
                    stage_half(Vb + (size_t)(q * 128) * S_ + (tt + 1) * 64, S_,
                               &Vs[cur ^ 1][q][0], w, lane);
            }
            f32x4 sac[2][2] = {};
            __builtin_amdgcn_s_setprio(1);
            #pragma unroll
            for (int ks = 0; ks < 2; ++ks)
                #pragma unroll
                for (int nj = 0; nj < 2; ++nj) {
                    bf16x8 kf = fragS(Ks, sc * 32 + nj * 16 + fr, ks, fg);
                    #pragma unroll
                    for (int mi = 0; mi < 2; ++mi)
                        sac[mi][nj] = mfma16(qf[mi][ks], kf, sac[mi][nj]);
                }
            __builtin_amdgcn_s_setprio(0);
            bool dg = (tt >= 2 * mt);   // block-uniform: only last 2 tiles touch diagonal
            if (dg) {
                #pragma unroll
                for (int mi = 0; mi < 2; ++mi)
                    #pragma unroll
                    for (int nj = 0; nj < 2; ++nj)
                        #pragma unroll
                        for (int jj = 0; jj < 4; ++jj) {
                            int srow = sr * 32 + mi * 16 + fg * 4 + jj;
                            int col = sc * 32 + nj * 16 + fr;
                            float p = exp2f(sac[mi][nj][jj]);
                            if (tt * 64 + col > m0 + srow) p = 0.f;
                            lsum[mi][jj] += p;
                            Ps[srow * 64 + (col ^ (fg << 4))] = (__bf16)p;
                        }
            } else {
                #pragma unroll
                for (int mi = 0; mi < 2; ++mi)
                    #pragma unroll
                    for (int nj = 0; nj < 2; ++nj)
                        #pragma unroll
                        for (int jj = 0; jj < 4; ++jj) {
                            int srow = sr * 32 + mi * 16 + fg * 4 + jj;
                            int col = sc * 32 + nj * 16 + fr;
                            float p = exp2f(sac[mi][nj][jj]);
                            lsum[mi][jj] += p;
                            Ps[srow * 64 + (col ^ (fg << 4))] = (__bf16)p;
                        }
            }
            asm volatile("s_waitcnt lgkmcnt(0)" ::: "memory");
            __builtin_amdgcn_s_barrier();
            __builtin_amdgcn_sched_barrier(0);
            // ---- phase B: K(t+1) reg->LDS; PV ----
            if (pre) {
                asm volatile("s_waitcnt vmcnt(8)" ::: "memory");   // drain kreg(t+1)
                *(uint4*)(Ks + w * 512 + lane * 8) = kreg;
                if (tt + 2 < NT)
                    kreg = *(const uint4*)(kpb + (size_t)((tt + 2) * 64 + kr) * (H_ * A_) +
                                           h * A_ + ksl * 8);
            }
            __builtin_amdgcn_s_setprio(1);
            const __bf16* Vh = &Vs[cur][wc][0];
            #pragma unroll
            for (int ks = 0; ks < 2; ++ks) {
                bf16x8 pa[4], vf[8];
                #pragma unroll
                for (int mi = 0; mi < 4; ++mi) {
                    int r = wr * 64 + mi * 16 + fr;
                    int g = (ks * 4 + fg) ^ (((fr >> 2) & 3) << 1);
                    pa[mi] = *(const bf16x8*)(Ps + r * 64 + g * 8);
                }
                #pragma unroll
                for (int nj = 0; nj < 8; ++nj)
                    vf[nj] = fragS(Vh, nj * 16 + fr, ks, fg);
                #pragma unroll
                for (int mi = 0; mi < 4; ++mi)
                    #pragma unroll
                    for (int nj = 0; nj < 8; ++nj)
                        acc[mi][nj] = mfma16(pa[mi], vf[nj], acc[mi][nj]);
            }
            __builtin_amdgcn_s_setprio(0);
            __builtin_amdgcn_sched_barrier(0);
            cur ^= 1;
        }
        // ---- row sums: shfl over fr, combine the 2 col-waves via LDS ----
        #pragma unroll
        for (int mi = 0; mi < 2; ++mi)
            #pragma unroll
            for (int jj = 0; jj < 4; ++jj) {
                float v = lsum[mi][jj];
                v += __shfl_xor(v, 1);
                v += __shfl_xor(v, 2);
                v += __shfl_xor(v, 4);
                v += __shfl_xor(v, 8);
                if (fr == 0) lpar[sr * 32 + mi * 16 + fg * 4 + jj][sc] = v;
            }
        asm volatile("s_waitcnt lgkmcnt(0)" ::: "memory");
        __builtin_amdgcn_s_barrier();
        // ---- epilogue: normalize + store ----
        #pragma unroll
        for (int mi = 0; mi < 4; ++mi)
            #pragma unroll
            for (int jj = 0; jj < 4; ++jj) {
                int row = wr * 64 + mi * 16 + fg * 4 + jj;
                float il = 1.f / (lpar[row][0] + lpar[row][1]);
                int m = m0 + row;
                #pragma unroll
                for (int nj = 0; nj < 8; ++nj) {
                    int n = n0 + wc * 128 + nj * 16 + fr;
                    ob[(size_t)m * D_ + n] = (__bf16)(acc[mi][nj][jj] * il);
                }
            }
        __builtin_amdgcn_s_barrier();  // Ps/lpar/Ks reuse across segs
    }
}

// ---------------- per-head Wo GEMM + bias + relu -> bf16 partials, 256^2 8-phase ----------------
__global__ __launch_bounds__(512) void k_headsum(
    const __bf16* __restrict__ att, const __bf16* __restrict__ Wot,
    const float* __restrict__ bo, __bf16* __restrict__ asum) {
    __shared__ __bf16 L[2][4][8192];
    int bid = blockIdx.x;                    // 512 blocks
    int xcd = bid & 7, slot = bid >> 3;      // slot 0..63
    int p = xcd * 2 + (slot >> 5);           // head 0..15
    int rem = slot & 31;
    int mt = rem >> 2;                       // 0..7
    int n0 = (rem & 3) * 256;
    int m0 = mt * 256;
    int t = threadIdx.x, lane = t & 63, w = t >> 6;
    int wr = w >> 2, wc = w & 3;
    int fr = lane & 15, fg = lane >> 4;
    const __bf16* Ab = att + ((size_t)p * S_ + m0) * D_;
    const __bf16* Bb = Wot + ((size_t)p * D_ + n0) * D_;
    float bv4[4];
    #pragma unroll
    for (int j = 0; j < 4; ++j)
        bv4[j] = bo[(size_t)p * D_ + n0 + wc * 64 + j * 16 + fr];
    f32x4 acc[8][4] = {};
    auto stg = [&](int tt, int h, int buf) {
        const __bf16* s = (h < 2) ? (Ab + (size_t)(h * 128) * D_ + tt * 64)
                                  : (Bb + (size_t)((h - 2) * 128) * D_ + tt * 64);
        stage_half(s, D_, &L[buf][h][0], w, lane);
    };
    auto loads = [&](const __bf16* Ah, const __bf16* Bh, int rb0, int mh, int nh,
                     bf16x8 (&af)[4][2], bf16x8 (&bv)[2][2]) {
        #pragma unroll
        for (int i = 0; i < 4; ++i)
            #pragma unroll
            for (int ks = 0; ks < 2; ++ks)
                af[i][ks] = fragS(Ah, mh * 64 + i * 16 + fr, ks, fg);
        #pragma unroll
        for (int j = 0; j < 2; ++j)
            #pragma unroll
            for (int ks = 0; ks < 2; ++ks)
                bv[j][ks] = fragS(Bh, rb0 + nh * 32 + j * 16 + fr, ks, fg);
    };
    stg(0, 0, 0); stg(0, 1, 0); stg(0, 2, 0); stg(0, 3, 0);
    int cur = 0;
    const int nt = D_ / 64;
    for (int tt = 0; tt < nt; ++tt) {
        bool pre = (tt + 1 < nt);
        const __bf16* Ah = &L[cur][wr][0];
        const __bf16* Bh = &L[cur][2 + (wc >> 1)][0];
        int rb0 = (wc & 1) * 64;
        #pragma unroll
        for (int ph = 0; ph < 4; ++ph) {
            const int mh = ph >> 1, nh = ph & 1;
            bf16x8 af[4][2], bv[2][2];
            if (ph == 0) {
                if (pre) {
                    stg(tt + 1, 0, cur ^ 1);
                    stg(tt + 1, 1, cur ^ 1);
                    stg(tt + 1, 2, cur ^ 1);
                    stg(tt + 1, 3, cur ^ 1);
                    asm volatile("s_waitcnt vmcnt(8)" ::: "memory");
                } else {
                    asm volatile("s_waitcnt vmcnt(0)" ::: "memory");
                }
                __builtin_amdgcn_s_barrier();
                __builtin_amdgcn_sched_barrier(0);
                loads(Ah, Bh, rb0, mh, nh, af, bv);
            } else {
                loads(Ah, Bh, rb0, mh, nh, af, bv);
                __builtin_amdgcn_s_barrier();
                __builtin_amdgcn_sched_barrier(0);
            }
            __builtin_amdgcn_s_setprio(1);
            #pragma unroll
            for (int i = 0; i < 4; ++i)
                #pragma unroll
                for (int j = 0; j < 2; ++j) {
                    acc[mh * 4 + i][nh * 2 + j] =
                        mfma16(af[i][0], bv[j][0], acc[mh * 4 + i][nh * 2 + j]);
                    acc[mh * 4 + i][nh * 2 + j] =
                        mfma16(af[i][1], bv[j][1], acc[mh * 4 + i][nh * 2 + j]);
                }
            __builtin_amdgcn_s_setprio(0);
            __builtin_amdgcn_sched_barrier(0);
            __builtin_amdgcn_s_barrier();
        }
        cur ^= 1;
    }
    __bf16* dst = asum + ((size_t)p * S_ + m0) * D_;
    #pragma unroll
    for (int mi = 0; mi < 8; ++mi)
        #pragma unroll
        for (int jj = 0; jj < 4; ++jj) {
            int mr = wr * 128 + mi * 16 + fg * 4 + jj;
            #pragma unroll
            for (int nj = 0; nj < 4; ++nj) {
                int nc = n0 + wc * 64 + nj * 16 + fr;
                dst[(size_t)mr * D_ + nc] = (__bf16)fmaxf(acc[mi][nj][jj] + bv4[nj], 0.f);
            }
        }
}

// ---------------- residual + 16-partial bf16 sum + LayerNorm (per batch) ----------------
__global__ __launch_bounds__(256) void k_ln(
    const float* __restrict__ x1b, const __bf16* __restrict__ parts,
    const float* __restrict__ gamma, const float* __restrict__ beta,
    float* __restrict__ outb) {
    int row = blockIdx.x;
    size_t base = (size_t)row * D_;
    int c = threadIdx.x * 4;
    float4 a = *(const float4*)(x1b + base + c);
    float x[4] = {a.x, a.y, a.z, a.w};
    #pragma unroll
    for (int p = 0; p < H_; ++p) {
        bf16x4 v = *(const bf16x4*)(parts + ((size_t)p * S_ + row) * D_ + c);
        x[0] += (float)v[0]; x[1] += (float)v[1];
        x[2] += (float)v[2]; x[3] += (float)v[3];
    }
    float sm = x[0] + x[1] + x[2] + x[3];
    float s2 = x[0] * x[0] + x[1] * x[1] + x[2] * x[2] + x[3] * x[3];
    #pragma unroll
    for (int m = 32; m >= 1; m >>= 1) {
        sm += __shfl_xor(sm, m);
        s2 += __shfl_xor(s2, m);
    }
    __shared__ float r1[4], r2[4];
    int w = threadIdx.x >> 6;
    if ((threadIdx.x & 63) == 0) { r1[w] = sm; r2[w] = s2; }
    __syncthreads();
    sm = r1[0] + r1[1] + r1[2] + r1[3];
    s2 = r2[0] + r2[1] + r2[2] + r2[3];
    float mean = sm * (1.f / D_);
    float var = s2 * (1.f / D_) - mean * mean;
    float rstd = rsqrtf(var + LN_EPS);
    #pragma unroll
    for (int jj = 0; jj < 4; ++jj)
        outb[base + c + jj] = gamma[c + jj] * (x[jj] - mean) * rstd + beta[c + jj];
}

// ---------------- host ----------------
extern "C" void kernel_launch(void* const* d_in, const int* in_sizes, int n_in,
                              void* d_out, int out_size, void* d_ws, size_t ws_size,
                              hipStream_t stream) {
    (void)in_sizes; (void)n_in; (void)out_size; (void)ws_size;
    const float* qin   = (const float*)d_in[0];
    const float* kvin  = (const float*)d_in[1];
    const float* Wq    = (const float*)d_in[2];
    const float* bq    = (const float*)d_in[3];
    const float* Wk    = (const float*)d_in[4];
    const float* bk    = (const float*)d_in[5];
    const float* Wo    = (const float*)d_in[6];
    const float* bo    = (const float*)d_in[7];
    const float* gamma = (const float*)d_in[8];
    const float* beta  = (const float*)d_in[9];
    float* out = (float*)d_out;
    char* ws = (char*)d_ws;

    size_t off = 0;
    auto alloc = [&](size_t bytes) {
        size_t o = off;
        off += (bytes + 255) & ~(size_t)255;
        return o;
    };
    size_t o_wqt = alloc((size_t)H_ * A_ * D_ * 2);
    size_t o_wkt = alloc((size_t)H_ * A_ * D_ * 2);
    size_t o_wot = alloc((size_t)H_ * D_ * D_ * 2);
    size_t o_kvt = alloc((size_t)B_ * D_ * S_ * 2);
    size_t o_qp  = alloc((size_t)B_ * S_ * H_ * A_ * 2);
    size_t o_kp  = alloc((size_t)B_ * S_ * H_ * A_ * 2);
    size_t o_att = alloc((size_t)H_ * S_ * D_ * 2);
    // region X: qb+kvb (proj inputs) then asum (bf16 partials) — disjoint lifetimes
    size_t xbytes_qb = (size_t)B_ * S_ * D_ * 2 * 2;
    size_t xbytes_as = (size_t)H_ * S_ * D_ * 2;
    size_t o_x = alloc(xbytes_qb > xbytes_as ? xbytes_qb : xbytes_as);

    __bf16* wqt = (__bf16*)(ws + o_wqt);
    __bf16* wkt = (__bf16*)(ws + o_wkt);
    __bf16* wot = (__bf16*)(ws + o_wot);
    __bf16* kvt = (__bf16*)(ws + o_kvt);
    __bf16* qp  = (__bf16*)(ws + o_qp);
    __bf16* kp  = (__bf16*)(ws + o_kp);
    __bf16* att = (__bf16*)(ws + o_att);
    __bf16* qb  = (__bf16*)(ws + o_x);
    __bf16* kvb = qb + (size_t)B_ * S_ * D_;
    __bf16* asum = (__bf16*)(ws + o_x);

    k_tr_cvt2<<<dim3(A_ / 32, D_ / 32, 2 * H_), dim3(32, 8), 0, stream>>>(
        Wq, Wk, wqt, wkt, D_, A_);
    k_tr_cvt<<<dim3(D_ / 32, D_ / 32, H_), dim3(32, 8), 0, stream>>>(Wo, wot, D_, D_);
    // kv: one read -> transposed kvt + linear kvb
    k_kv_prep<<<dim3(D_ / 32, S_ / 32, B_), dim3(32, 8), 0, stream>>>(kvin, kvt, kvb);
    int n8 = B_ * S_ * D_ / 8;
    k_cvt<<<(n8 + 255) / 256, 256, 0, stream>>>(qin, qb, n8);
    k_proj<<<dim3(8, 64, 2), 256, 0, stream>>>(qb, kvb, wqt, wkt, bq, bk, qp, kp);

    for (int b = 0; b < B_; ++b) {
        const __bf16* qpb  = qp + (size_t)b * S_ * (H_ * A_);
        const __bf16* kpb  = kp + (size_t)b * S_ * (H_ * A_);
        const __bf16* kvtb = kvt + (size_t)b * D_ * S_;
        k_fattn<<<256, 512, 0, stream>>>(qpb, kpb, kvtb, att);
        k_headsum<<<512, 512, 0, stream>>>(att, wot, bo, asum);
        k_ln<<<S_, 256, 0, stream>>>(qin + (size_t)b * S_ * D_, asum, gamma, beta,
                                     out + (size_t)b * S_ * D_);
    }
}

// Round 17
// 997.400 us; speedup vs baseline: 1.0652x; 1.0139x over previous
//
#include <hip/hip_runtime.h>
#include <stdint.h>

#define B_ 4
#define S_ 2048
#define D_ 1024
#define H_ 16
#define A_ 64
#define LN_EPS 1e-3f

typedef __bf16 bf16x8 __attribute__((ext_vector_type(8)));
typedef __bf16 bf16x4 __attribute__((ext_vector_type(4)));
typedef float f32x4 __attribute__((ext_vector_type(4)));

__device__ __forceinline__ f32x4 mfma16(bf16x8 a, bf16x8 b, f32x4 c) {
    return __builtin_amdgcn_mfma_f32_16x16x32_bf16(a, b, c, 0, 0, 0);
}
__device__ __forceinline__ void glds16(const void* g, void* l) {
    __builtin_amdgcn_global_load_lds(
        (const __attribute__((address_space(1))) void*)g,
        (__attribute__((address_space(3))) void*)l, 16, 0, 0);
}

// ---- swizzled [128][64] half-tile staging ----
#define SWZ(slot, r) ((slot) ^ (((r) & 1) << 2) ^ (((r) >> 1) & 3))
__device__ __forceinline__ void stage_half(const __bf16* __restrict__ src, size_t ld,
                                           __bf16* lhalf, int w, int lane) {
    #pragma unroll
    for (int i = 0; i < 2; ++i) {
        int ch = w * 2 + i;
        int r = ch * 8 + (lane >> 3);
        int sl = SWZ(lane & 7, r);
        glds16(src + (size_t)r * ld + sl * 8, lhalf + ch * 512);
    }
}
__device__ __forceinline__ bf16x8 fragS(const __bf16* h, int r, int ks, int fg) {
    return *(const bf16x8*)(h + r * 64 + SWZ(ks * 4 + fg, r) * 8);
}

// ---------------- tiled transpose + f32->bf16 convert ----------------
__global__ void k_tr_cvt(const float* __restrict__ in, __bf16* __restrict__ out,
                         int R, int C) {
    __shared__ float tile[32][33];
    size_t gbase = (size_t)blockIdx.z * R * C;
    int r0 = blockIdx.y * 32, c0 = blockIdx.x * 32;
    #pragma unroll
    for (int i = threadIdx.y; i < 32; i += 8)
        tile[i][threadIdx.x] = in[gbase + (size_t)(r0 + i) * C + c0 + threadIdx.x];
    __syncthreads();
    #pragma unroll
    for (int i = threadIdx.y; i < 32; i += 8)
        out[gbase + (size_t)(c0 + i) * R + r0 + threadIdx.x] = (__bf16)tile[threadIdx.x][i];
}
__global__ void k_tr_cvt2(const float* __restrict__ in0, const float* __restrict__ in1,
                          __bf16* __restrict__ out0, __bf16* __restrict__ out1,
                          int R, int C) {
    __shared__ float tile[32][33];
    int z = blockIdx.z;
    const float* in = (z < H_) ? in0 : in1;
    __bf16* out = (z < H_) ? out0 : out1;
    size_t gbase = (size_t)(z & (H_ - 1)) * R * C;
    int r0 = blockIdx.y * 32, c0 = blockIdx.x * 32;
    #pragma unroll
    for (int i = threadIdx.y; i < 32; i += 8)
        tile[i][threadIdx.x] = in[gbase + (size_t)(r0 + i) * C + c0 + threadIdx.x];
    __syncthreads();
    #pragma unroll
    for (int i = threadIdx.y; i < 32; i += 8)
        out[gbase + (size_t)(c0 + i) * R + r0 + threadIdx.x] = (__bf16)tile[threadIdx.x][i];
}

// ---------------- kv prep: one read of kvin -> kvt (transposed) + kvb (linear) ----------------
__global__ void k_kv_prep(const float* __restrict__ in, __bf16* __restrict__ outT,
                          __bf16* __restrict__ outL) {
    __shared__ float tile[32][33];
    size_t gbase = (size_t)blockIdx.z * S_ * D_;
    int r0 = blockIdx.y * 32, c0 = blockIdx.x * 32;
    #pragma unroll
    for (int i = threadIdx.y; i < 32; i += 8) {
        float v = in[gbase + (size_t)(r0 + i) * D_ + c0 + threadIdx.x];
        tile[i][threadIdx.x] = v;
        outL[gbase + (size_t)(r0 + i) * D_ + c0 + threadIdx.x] = (__bf16)v;
    }
    __syncthreads();
    #pragma unroll
    for (int i = threadIdx.y; i < 32; i += 8)
        outT[gbase + (size_t)(c0 + i) * S_ + r0 + threadIdx.x] = (__bf16)tile[threadIdx.x][i];
}

// ---------------- elementwise f32 -> bf16 ----------------
__global__ void k_cvt(const float* __restrict__ in, __bf16* __restrict__ out, int n8) {
    int i = blockIdx.x * blockDim.x + threadIdx.x;
    if (i >= n8) return;
    const float4* p = (const float4*)(in + (size_t)i * 8);
    float4 f0 = p[0], f1 = p[1];
    __bf16 v[8] = {(__bf16)f0.x, (__bf16)f0.y, (__bf16)f0.z, (__bf16)f0.w,
                   (__bf16)f1.x, (__bf16)f1.y, (__bf16)f1.z, (__bf16)f1.w};
    *(uint4*)(out + (size_t)i * 8) = *(const uint4*)v;
}

// ---------------- Q/K projection: 256^2 8-phase (headsum skeleton, param change) ----------------
// q pre-scaled by (1/sqrt(A)) * log2(e) so fattn uses exp2 directly.
// 1D grid 256 blocks: which = xcd>>2 (XCDs 0-3 q, 4-7 kv), n0 = (xcd&3)*256
// (B-panel 512KB L2-resident per XCD), mt = slot (0..31).
__global__ __launch_bounds__(512) void k_proj(
    const __bf16* __restrict__ qb, const __bf16* __restrict__ kvb,
    const __bf16* __restrict__ wqt, const __bf16* __restrict__ wkt,
    const float* __restrict__ bq, const float* __restrict__ bk,
    __bf16* __restrict__ qp, __bf16* __restrict__ kp) {
    __shared__ __bf16 L[2][4][8192];
    int bid = blockIdx.x;                    // 256 blocks
    int xcd = bid & 7, slot = bid >> 3;      // slot 0..31 = mt
    int which = xcd >> 2;
    int n0 = (xcd & 3) * 256;
    int m0 = slot * 256;
    const __bf16* Ab = (which ? kvb : qb) + (size_t)m0 * D_;
    const __bf16* Bb = (which ? wkt : wqt) + (size_t)n0 * D_;
    const float* bias = which ? bk : bq;
    float scale = which ? 1.0f : 0.18033688011112042f;  // 0.125 * log2(e)
    __bf16* outp = which ? kp : qp;
    int t = threadIdx.x, lane = t & 63, w = t >> 6;
    int wr = w >> 2, wc = w & 3;
    int fr = lane & 15, fg = lane >> 4;
    float bv4[4];
    #pragma unroll
    for (int j = 0; j < 4; ++j)
        bv4[j] = bias[n0 + wc * 64 + j * 16 + fr];
    f32x4 acc[8][4] = {};
    auto stg = [&](int tt, int h, int buf) {
        const __bf16* s = (h < 2) ? (Ab + (size_t)(h * 128) * D_ + tt * 64)
                                  : (Bb + (size_t)((h - 2) * 128) * D_ + tt * 64);
        stage_half(s, D_, &L[buf][h][0], w, lane);
    };
    auto loads = [&](const __bf16* Ah, const __bf16* Bh, int rb0, int mh, int nh,
                     bf16x8 (&af)[4][2], bf16x8 (&bv)[2][2]) {
        #pragma unroll
        for (int i = 0; i < 4; ++i)
            #pragma unroll
            for (int ks = 0; ks < 2; ++ks)
                af[i][ks] = fragS(Ah, mh * 64 + i * 16 + fr, ks, fg);
        #pragma unroll
        for (int j = 0; j < 2; ++j)
            #pragma unroll
            for (int ks = 0; ks < 2; ++ks)
                bv[j][ks] = fragS(Bh, rb0 + nh * 32 + j * 16 + fr, ks, fg);
    };
    stg(0, 0, 0); stg(0, 1, 0); stg(0, 2, 0); stg(0, 3, 0);
    int cur = 0;
    const int nt = D_ / 64;
    for (int tt = 0; tt < nt; ++tt) {
        bool pre = (tt + 1 < nt);
        const __bf16* Ah = &L[cur][wr][0];
        const __bf16* Bh = &L[cur][2 + (wc >> 1)][0];
        int rb0 = (wc & 1) * 64;
        #pragma unroll
        for (int ph = 0; ph < 4; ++ph) {
            const int mh = ph >> 1, nh = ph & 1;
            bf16x8 af[4][2], bv[2][2];
            if (ph == 0) {
                if (pre) {
                    stg(tt + 1, 0, cur ^ 1);
                    stg(tt + 1, 1, cur ^ 1);
                    stg(tt + 1, 2, cur ^ 1);
                    stg(tt + 1, 3, cur ^ 1);
                    asm volatile("s_waitcnt vmcnt(8)" ::: "memory");
                } else {
                    asm volatile("s_waitcnt vmcnt(0)" ::: "memory");
                }
                __builtin_amdgcn_s_barrier();
                __builtin_amdgcn_sched_barrier(0);
                loads(Ah, Bh, rb0, mh, nh, af, bv);
            } else {
                loads(Ah, Bh, rb0, mh, nh, af, bv);
                __builtin_amdgcn_s_barrier();
                __builtin_amdgcn_sched_barrier(0);
            }
            __builtin_amdgcn_s_setprio(1);
            #pragma unroll
            for (int i = 0; i < 4; ++i)
                #pragma unroll
                for (int j = 0; j < 2; ++j) {
                    acc[mh * 4 + i][nh * 2 + j] =
                        mfma16(af[i][0], bv[j][0], acc[mh * 4 + i][nh * 2 + j]);
                    acc[mh * 4 + i][nh * 2 + j] =
                        mfma16(af[i][1], bv[j][1], acc[mh * 4 + i][nh * 2 + j]);
                }
            __builtin_amdgcn_s_setprio(0);
            __builtin_amdgcn_sched_barrier(0);
            __builtin_amdgcn_s_barrier();
        }
        cur ^= 1;
    }
    __bf16* dst = outp + (size_t)m0 * (H_ * A_);
    #pragma unroll
    for (int mi = 0; mi < 8; ++mi)
        #pragma unroll
        for (int jj = 0; jj < 4; ++jj) {
            int mr = wr * 128 + mi * 16 + fg * 4 + jj;
            #pragma unroll
            for (int nj = 0; nj < 4; ++nj) {
                int nc = n0 + wc * 64 + nj * 16 + fr;
                dst[(size_t)mr * (H_ * A_) + nc] =
                    (__bf16)((acc[mi][nj][jj] + bv4[nj]) * scale);
            }
        }
}

// ---------------- fused flash attention, BN=512, XCD-local, full-tile V cover ----------------
// R16-exact (measured best: 125.0 us/dispatch).
// Ledger: A(t) entry [V(t)x8, kreg(t+1)] -> vmcnt(1) drains V(t); post-barrier
// issue V(t+1); B(t) vmcnt(8) drains kreg(t+1); Ks<-kreg; load kreg(t+2).
__global__ __launch_bounds__(512, 1) void k_fattn(
    const __bf16* __restrict__ qpb, const __bf16* __restrict__ kpb,
    const __bf16* __restrict__ kvtb, __bf16* __restrict__ att) {
    __shared__ __bf16 Ks[64 * 64];          // 8 KB, single buffer
    __shared__ __bf16 Vs[2][4][128 * 64];   // 128 KB
    __shared__ __bf16 Ps[128 * 64];         // 16 KB (also Q staging)
    __shared__ float lpar[128][2];          // 1 KB
    int bid = blockIdx.x;                   // 256 blocks
    int xcd = bid & 7, slot = bid >> 3;     // slot 0..31
    int n0 = (xcd & 1) * 512;
    int h = (xcd >> 1) * 4 + (slot >> 3);
    int yp = slot & 7;
    int t = threadIdx.x, lane = t & 63, w = t >> 6;
    int fr = lane & 15, fg = lane >> 4;
    int wr = w >> 2, wc = w & 3;   // PV: rows wr*64, cols wc*128
    int sr = w >> 1, sc = w & 1;   // QK^T: rows sr*32, cols sc*32
    const __bf16* Vb = kvtb + (size_t)n0 * S_;
    __bf16* ob = att + (size_t)h * S_ * D_;
    int kr = w * 8 + (lane >> 3);       // K stage row (64 rows over 8 waves)
    int ksl = SWZ(lane & 7, kr);        // K stage source slot

    #pragma unroll 1
    for (int seg = 0; seg < 2; ++seg) {
        int mt = seg ? (15 - yp) : yp;
        int m0 = mt * 128;
        int NT = (mt + 1) * 2;
        // ---- prologue: Q -> Ps -> regs; K0 glds; V0 glds; K1 -> reg ----
        stage_half(qpb + (size_t)m0 * (H_ * A_) + h * A_, H_ * A_, Ps, w, lane);
        glds16(kpb + (size_t)kr * (H_ * A_) + h * A_ + ksl * 8, Ks + w * 512);
        asm volatile("s_waitcnt vmcnt(0)" ::: "memory");
        __builtin_amdgcn_s_barrier();
        bf16x8 qf[2][2];
        #pragma unroll
        for (int mi = 0; mi < 2; ++mi)
            #pragma unroll
            for (int ks = 0; ks < 2; ++ks)
                qf[mi][ks] = fragS(Ps, sr * 32 + mi * 16 + fr, ks, fg);
        asm volatile("s_waitcnt lgkmcnt(0)" ::: "memory");
        #pragma unroll
        for (int q = 0; q < 4; ++q)
            stage_half(Vb + (size_t)(q * 128) * S_, S_, &Vs[0][q][0], w, lane);
        uint4 kreg = {0, 0, 0, 0};
        if (NT > 1)
            kreg = *(const uint4*)(kpb + (size_t)(64 + kr) * (H_ * A_) + h * A_ + ksl * 8);
        __builtin_amdgcn_s_barrier();  // Q reads done before P~ writes
        __builtin_amdgcn_sched_barrier(0);
        f32x4 acc[4][8] = {};
        float lsum[2][4] = {};
        int cur = 0;
        for (int tt = 0; tt < NT; ++tt) {
            bool pre = (tt + 1 < NT);
            // ---- phase A: wait V(t); issue V(t+1) post-barrier; QK^T + exp + P~ ----
            if (pre) {
                asm volatile("s_waitcnt vmcnt(1)" ::: "memory");   // drain V(t)x8
            } else {
                asm volatile("s_waitcnt vmcnt(0)" ::: "memory");
            }
            asm volatile("s_waitcnt lgkmcnt(0)" ::: "memory");
            __builtin_amdgcn_s_barrier();
            __builtin_amdgcn_sched_barrier(0);
            if (pre) {
                #pragma unroll
                for (int q = 0; q < 4; ++q)
                    stage_half(Vb + (size_t)(q * 128) * S_ + (tt + 1) * 64, S_,
                               &Vs[cur ^ 1][q][0], w, lane);
            }
            f32x4 sac[2][2] = {};
            __builtin_amdgcn_s_setprio(1);
            #pragma unroll
            for (int ks = 0; ks < 2; ++ks)
                #pragma unroll
                for (int nj = 0; nj < 2; ++nj) {
                    bf16x8 kf = fragS(Ks, sc * 32 + nj * 16 + fr, ks, fg);
                    #pragma unroll
                    for (int mi = 0; mi < 2; ++mi)
                        sac[mi][nj] = mfma16(qf[mi][ks], kf, sac[mi][nj]);
                }
            __builtin_amdgcn_s_setprio(0);
            bool dg = (tt >= 2 * mt);   // block-uniform: only last 2 tiles touch diagonal
            if (dg) {
                #pragma unroll
                for (int mi = 0; mi < 2; ++mi)
                    #pragma unroll
                    for (int nj = 0; nj < 2; ++nj)
                        #pragma unroll
                        for (int jj = 0; jj < 4; ++jj) {
                            int srow = sr * 32 + mi * 16 + fg * 4 + jj;
                            int col = sc * 32 + nj * 16 + fr;
                            float p = exp2f(sac[mi][nj][jj]);
                            if (tt * 64 + col > m0 + srow) p = 0.f;
                            lsum[mi][jj] += p;
                            Ps[srow * 64 + (col ^ (fg << 4))] = (__bf16)p;
                        }
            } else {
                #pragma unroll
                for (int mi = 0; mi < 2; ++mi)
                    #pragma unroll
                    for (int nj = 0; nj < 2; ++nj)
                        #pragma unroll
                        for (int jj = 0; jj < 4; ++jj) {
                            int srow = sr * 32 + mi * 16 + fg * 4 + jj;
                            int col = sc * 32 + nj * 16 + fr;
                            float p = exp2f(sac[mi][nj][jj]);
                            lsum[mi][jj] += p;
                            Ps[srow * 64 + (col ^ (fg << 4))] = (__bf16)p;
                        }
            }
            asm volatile("s_waitcnt lgkmcnt(0)" ::: "memory");
            __builtin_amdgcn_s_barrier();
            __builtin_amdgcn_sched_barrier(0);
            // ---- phase B: K(t+1) reg->LDS; PV ----
            if (pre) {
                asm volatile("s_waitcnt vmcnt(8)" ::: "memory");   // drain kreg(t+1)
                *(uint4*)(Ks + w * 512 + lane * 8) = kreg;
                if (tt + 2 < NT)
                    kreg = *(const uint4*)(kpb + (size_t)((tt + 2) * 64 + kr) * (H_ * A_) +
                                           h * A_ + ksl * 8);
            }
            __builtin_amdgcn_s_setprio(1);
            const __bf16* Vh = &Vs[cur][wc][0];
            #pragma unroll
            for (int ks = 0; ks < 2; ++ks) {
                bf16x8 pa[4], vf[8];
                #pragma unroll
                for (int mi = 0; mi < 4; ++mi) {
                    int r = wr * 64 + mi * 16 + fr;
                    int g = (ks * 4 + fg) ^ (((fr >> 2) & 3) << 1);
                    pa[mi] = *(const bf16x8*)(Ps + r * 64 + g * 8);
                }
                #pragma unroll
                for (int nj = 0; nj < 8; ++nj)
                    vf[nj] = fragS(Vh, nj * 16 + fr, ks, fg);
                #pragma unroll
                for (int mi = 0; mi < 4; ++mi)
                    #pragma unroll
                    for (int nj = 0; nj < 8; ++nj)
                        acc[mi][nj] = mfma16(pa[mi], vf[nj], acc[mi][nj]);
            }
            __builtin_amdgcn_s_setprio(0);
            __builtin_amdgcn_sched_barrier(0);
            cur ^= 1;
        }
        // ---- row sums: shfl over fr, combine the 2 col-waves via LDS ----
        #pragma unroll
        for (int mi = 0; mi < 2; ++mi)
            #pragma unroll
            for (int jj = 0; jj < 4; ++jj) {
                float v = lsum[mi][jj];
                v += __shfl_xor(v, 1);
                v += __shfl_xor(v, 2);
                v += __shfl_xor(v, 4);
                v += __shfl_xor(v, 8);
                if (fr == 0) lpar[sr * 32 + mi * 16 + fg * 4 + jj][sc] = v;
            }
        asm volatile("s_waitcnt lgkmcnt(0)" ::: "memory");
        __builtin_amdgcn_s_barrier();
        // ---- epilogue: normalize + store ----
        #pragma unroll
        for (int mi = 0; mi < 4; ++mi)
            #pragma unroll
            for (int jj = 0; jj < 4; ++jj) {
                int row = wr * 64 + mi * 16 + fg * 4 + jj;
                float il = 1.f / (lpar[row][0] + lpar[row][1]);
                int m = m0 + row;
                #pragma unroll
                for (int nj = 0; nj < 8; ++nj) {
                    int n = n0 + wc * 128 + nj * 16 + fr;
                    ob[(size_t)m * D_ + n] = (__bf16)(acc[mi][nj][jj] * il);
                }
            }
        __builtin_amdgcn_s_barrier();  // Ps/lpar/Ks reuse across segs
    }
}

// ---------------- per-head Wo GEMM + bias + relu -> bf16 partials, 256^2 8-phase ----------------
__global__ __launch_bounds__(512) void k_headsum(
    const __bf16* __restrict__ att, const __bf16* __restrict__ Wot,
    const float* __restrict__ bo, __bf16* __restrict__ asum) {
    __shared__ __bf16 L[2][4][8192];
    int bid = blockIdx.x;                    // 512 blocks
    int xcd = bid & 7, slot = bid >> 3;      // slot 0..63
    int p = xcd * 2 + (slot >> 5);           // head 0..15
    int rem = slot & 31;
    int mt = rem >> 2;                       // 0..7
    int n0 = (rem & 3) * 256;
    int m0 = mt * 256;
    int t = threadIdx.x, lane = t & 63, w = t >> 6;
    int wr = w >> 2, wc = w & 3;
    int fr = lane & 15, fg = lane >> 4;
    const __bf16* Ab = att + ((size_t)p * S_ + m0) * D_;
    const __bf16* Bb = Wot + ((size_t)p * D_ + n0) * D_;
    float bv4[4];
    #pragma unroll
    for (int j = 0; j < 4; ++j)
        bv4[j] = bo[(size_t)p * D_ + n0 + wc * 64 + j * 16 + fr];
    f32x4 acc[8][4] = {};
    auto stg = [&](int tt, int h, int buf) {
        const __bf16* s = (h < 2) ? (Ab + (size_t)(h * 128) * D_ + tt * 64)
                                  : (Bb + (size_t)((h - 2) * 128) * D_ + tt * 64);
        stage_half(s, D_, &L[buf][h][0], w, lane);
    };
    auto loads = [&](const __bf16* Ah, const __bf16* Bh, int rb0, int mh, int nh,
                     bf16x8 (&af)[4][2], bf16x8 (&bv)[2][2]) {
        #pragma unroll
        for (int i = 0; i < 4; ++i)
            #pragma unroll
            for (int ks = 0; ks < 2; ++ks)
                af[i][ks] = fragS(Ah, mh * 64 + i * 16 + fr, ks, fg);
        #pragma unroll
        for (int j = 0; j < 2; ++j)
            #pragma unroll
            for (int ks = 0; ks < 2; ++ks)
                bv[j][ks] = fragS(Bh, rb0 + nh * 32 + j * 16 + fr, ks, fg);
    };
    stg(0, 0, 0); stg(0, 1, 0); stg(0, 2, 0); stg(0, 3, 0);
    int cur = 0;
    const int nt = D_ / 64;
    for (int tt = 0; tt < nt; ++tt) {
        bool pre = (tt + 1 < nt);
        const __bf16* Ah = &L[cur][wr][0];
        const __bf16* Bh = &L[cur][2 + (wc >> 1)][0];
        int rb0 = (wc & 1) * 64;
        #pragma unroll
        for (int ph = 0; ph < 4; ++ph) {
            const int mh = ph >> 1, nh = ph & 1;
            bf16x8 af[4][2], bv[2][2];
            if (ph == 0) {
                if (pre) {
                    stg(tt + 1, 0, cur ^ 1);
                    stg(tt + 1, 1, cur ^ 1);
                    stg(tt + 1, 2, cur ^ 1);
                    stg(tt + 1, 3, cur ^ 1);
                    asm volatile("s_waitcnt vmcnt(8)" ::: "memory");
                } else {
                    asm volatile("s_waitcnt vmcnt(0)" ::: "memory");
                }
                __builtin_amdgcn_s_barrier();
                __builtin_amdgcn_sched_barrier(0);
                loads(Ah, Bh, rb0, mh, nh, af, bv);
            } else {
                loads(Ah, Bh, rb0, mh, nh, af, bv);
                __builtin_amdgcn_s_barrier();
                __builtin_amdgcn_sched_barrier(0);
            }
            __builtin_amdgcn_s_setprio(1);
            #pragma unroll
            for (int i = 0; i < 4; ++i)
                #pragma unroll
                for (int j = 0; j < 2; ++j) {
                    acc[mh * 4 + i][nh * 2 + j] =
                        mfma16(af[i][0], bv[j][0], acc[mh * 4 + i][nh * 2 + j]);
                    acc[mh * 4 + i][nh * 2 + j] =
                        mfma16(af[i][1], bv[j][1], acc[mh * 4 + i][nh * 2 + j]);
                }
            __builtin_amdgcn_s_setprio(0);
            __builtin_amdgcn_sched_barrier(0);
            __builtin_amdgcn_s_barrier();
        }
        cur ^= 1;
    }
    __bf16* dst = asum + ((size_t)p * S_ + m0) * D_;
    #pragma unroll
    for (int mi = 0; mi < 8; ++mi)
        #pragma unroll
        for (int jj = 0; jj < 4; ++jj) {
            int mr = wr * 128 + mi * 16 + fg * 4 + jj;
            #pragma unroll
            for (int nj = 0; nj < 4; ++nj) {
                int nc = n0 + wc * 64 + nj * 16 + fr;
                dst[(size_t)mr * D_ + nc] = (__bf16)fmaxf(acc[mi][nj][jj] + bv4[nj], 0.f);
            }
        }
}

// ---------------- residual + 16-partial bf16 sum + LayerNorm (per batch) ----------------
__global__ __launch_bounds__(256) void k_ln(
    const float* __restrict__ x1b, const __bf16* __restrict__ parts,
    const float* __restrict__ gamma, const float* __restrict__ beta,
    float* __restrict__ outb) {
    int row = blockIdx.x;
    size_t base = (size_t)row * D_;
    int c = threadIdx.x * 4;
    float4 a = *(const float4*)(x1b + base + c);
    float x[4] = {a.x, a.y, a.z, a.w};
    #pragma unroll
    for (int p = 0; p < H_; ++p) {
        bf16x4 v = *(const bf16x4*)(parts + ((size_t)p * S_ + row) * D_ + c);
        x[0] += (float)v[0]; x[1] += (float)v[1];
        x[2] += (float)v[2]; x[3] += (float)v[3];
    }
    float sm = x[0] + x[1] + x[2] + x[3];
    float s2 = x[0] * x[0] + x[1] * x[1] + x[2] * x[2] + x[3] * x[3];
    #pragma unroll
    for (int m = 32; m >= 1; m >>= 1) {
        sm += __shfl_xor(sm, m);
        s2 += __shfl_xor(s2, m);
    }
    __shared__ float r1[4], r2[4];
    int w = threadIdx.x >> 6;
    if ((threadIdx.x & 63) == 0) { r1[w] = sm; r2[w] = s2; }
    __syncthreads();
    sm = r1[0] + r1[1] + r1[2] + r1[3];
    s2 = r2[0] + r2[1] + r2[2] + r2[3];
    float mean = sm * (1.f / D_);
    float var = s2 * (1.f / D_) - mean * mean;
    float rstd = rsqrtf(var + LN_EPS);
    #pragma unroll
    for (int jj = 0; jj < 4; ++jj)
        outb[base + c + jj] = gamma[c + jj] * (x[jj] - mean) * rstd + beta[c + jj];
}

// ---------------- host ----------------
extern "C" void kernel_launch(void* const* d_in, const int* in_sizes, int n_in,
                              void* d_out, int out_size, void* d_ws, size_t ws_size,
                              hipStream_t stream) {
    (void)in_sizes; (void)n_in; (void)out_size; (void)ws_size;
    const float* qin   = (const float*)d_in[0];
    const float* kvin  = (const float*)d_in[1];
    const float* Wq    = (const float*)d_in[2];
    const float* bq    = (const float*)d_in[3];
    const float* Wk    = (const float*)d_in[4];
    const float* bk    = (const float*)d_in[5];
    const float* Wo    = (const float*)d_in[6];
    const float* bo    = (const float*)d_in[7];
    const float* gamma = (const float*)d_in[8];
    const float* beta  = (const float*)d_in[9];
    float* out = (float*)d_out;
    char* ws = (char*)d_ws;

    size_t off = 0;
    auto alloc = [&](size_t bytes) {
        size_t o = off;
        off += (bytes + 255) & ~(size_t)255;
        return o;
    };
    size_t o_wqt = alloc((size_t)H_ * A_ * D_ * 2);
    size_t o_wkt = alloc((size_t)H_ * A_ * D_ * 2);
    size_t o_wot = alloc((size_t)H_ * D_ * D_ * 2);
    size_t o_kvt = alloc((size_t)B_ * D_ * S_ * 2);
    size_t o_qp  = alloc((size_t)B_ * S_ * H_ * A_ * 2);
    size_t o_kp  = alloc((size_t)B_ * S_ * H_ * A_ * 2);
    size_t o_att = alloc((size_t)H_ * S_ * D_ * 2);
    // region X: qb+kvb (proj inputs) then asum (bf16 partials) — disjoint lifetimes
    size_t xbytes_qb = (size_t)B_ * S_ * D_ * 2 * 2;
    size_t xbytes_as = (size_t)H_ * S_ * D_ * 2;
    size_t o_x = alloc(xbytes_qb > xbytes_as ? xbytes_qb : xbytes_as);

    __bf16* wqt = (__bf16*)(ws + o_wqt);
    __bf16* wkt = (__bf16*)(ws + o_wkt);
    __bf16* wot = (__bf16*)(ws + o_wot);
    __bf16* kvt = (__bf16*)(ws + o_kvt);
    __bf16* qp  = (__bf16*)(ws + o_qp);
    __bf16* kp  = (__bf16*)(ws + o_kp);
    __bf16* att = (__bf16*)(ws + o_att);
    __bf16* qb  = (__bf16*)(ws + o_x);
    __bf16* kvb = qb + (size_t)B_ * S_ * D_;
    __bf16* asum = (__bf16*)(ws + o_x);

    k_tr_cvt2<<<dim3(A_ / 32, D_ / 32, 2 * H_), dim3(32, 8), 0, stream>>>(
        Wq, Wk, wqt, wkt, D_, A_);
    k_tr_cvt<<<dim3(D_ / 32, D_ / 32, H_), dim3(32, 8), 0, stream>>>(Wo, wot, D_, D_);
    // kv: one read -> transposed kvt + linear kvb
    k_kv_prep<<<dim3(D_ / 32, S_ / 32, B_), dim3(32, 8), 0, stream>>>(kvin, kvt, kvb);
    int n8 = B_ * S_ * D_ / 8;
    k_cvt<<<(n8 + 255) / 256, 256, 0, stream>>>(qin, qb, n8);
    k_proj<<<256, 512, 0, stream>>>(qb, kvb, wqt, wkt, bq, bk, qp, kp);

    for (int b = 0; b < B_; ++b) {
        const __bf16* qpb  = qp + (size_t)b * S_ * (H_ * A_);
        const __bf16* kpb  = kp + (size_t)b * S_ * (H_ * A_);
        const __bf16* kvtb = kvt + (size_t)b * D_ * S_;
        k_fattn<<<256, 512, 0, stream>>>(qpb, kpb, kvtb, att);
        k_headsum<<<512, 512, 0, stream>>>(att, wot, bo, asum);
        k_ln<<<S_, 256, 0, stream>>>(qin + (size_t)b * S_ * D_, asum, gamma, beta,
                                     out + (size_t)b * S_ * D_);
    }
}

// Round 18
// 990.962 us; speedup vs baseline: 1.0721x; 1.0065x over previous
//
#include <hip/hip_runtime.h>
#include <stdint.h>

#define B_ 4
#define S_ 2048
#define D_ 1024
#define H_ 16
#define A_ 64
#define LN_EPS 1e-3f

typedef __bf16 bf16x8 __attribute__((ext_vector_type(8)));
typedef __bf16 bf16x4 __attribute__((ext_vector_type(4)));
typedef float f32x4 __attribute__((ext_vector_type(4)));

__device__ __forceinline__ f32x4 mfma16(bf16x8 a, bf16x8 b, f32x4 c) {
    return __builtin_amdgcn_mfma_f32_16x16x32_bf16(a, b, c, 0, 0, 0);
}
__device__ __forceinline__ void glds16(const void* g, void* l) {
    __builtin_amdgcn_global_load_lds(
        (const __attribute__((address_space(1))) void*)g,
        (__attribute__((address_space(3))) void*)l, 16, 0, 0);
}

// ---- swizzled [128][64] half-tile staging ----
#define SWZ(slot, r) ((slot) ^ (((r) & 1) << 2) ^ (((r) >> 1) & 3))
__device__ __forceinline__ void stage_half(const __bf16* __restrict__ src, size_t ld,
                                           __bf16* lhalf, int w, int lane) {
    #pragma unroll
    for (int i = 0; i < 2; ++i) {
        int ch = w * 2 + i;
        int r = ch * 8 + (lane >> 3);
        int sl = SWZ(lane & 7, r);
        glds16(src + (size_t)r * ld + sl * 8, lhalf + ch * 512);
    }
}
__device__ __forceinline__ bf16x8 fragS(const __bf16* h, int r, int ks, int fg) {
    return *(const bf16x8*)(h + r * 64 + SWZ(ks * 4 + fg, r) * 8);
}

// ---------------- tiled transpose + f32->bf16 convert ----------------
__global__ void k_tr_cvt(const float* __restrict__ in, __bf16* __restrict__ out,
                         int R, int C) {
    __shared__ float tile[32][33];
    size_t gbase = (size_t)blockIdx.z * R * C;
    int r0 = blockIdx.y * 32, c0 = blockIdx.x * 32;
    #pragma unroll
    for (int i = threadIdx.y; i < 32; i += 8)
        tile[i][threadIdx.x] = in[gbase + (size_t)(r0 + i) * C + c0 + threadIdx.x];
    __syncthreads();
    #pragma unroll
    for (int i = threadIdx.y; i < 32; i += 8)
        out[gbase + (size_t)(c0 + i) * R + r0 + threadIdx.x] = (__bf16)tile[threadIdx.x][i];
}
__global__ void k_tr_cvt2(const float* __restrict__ in0, const float* __restrict__ in1,
                          __bf16* __restrict__ out0, __bf16* __restrict__ out1,
                          int R, int C) {
    __shared__ float tile[32][33];
    int z = blockIdx.z;
    const float* in = (z < H_) ? in0 : in1;
    __bf16* out = (z < H_) ? out0 : out1;
    size_t gbase = (size_t)(z & (H_ - 1)) * R * C;
    int r0 = blockIdx.y * 32, c0 = blockIdx.x * 32;
    #pragma unroll
    for (int i = threadIdx.y; i < 32; i += 8)
        tile[i][threadIdx.x] = in[gbase + (size_t)(r0 + i) * C + c0 + threadIdx.x];
    __syncthreads();
    #pragma unroll
    for (int i = threadIdx.y; i < 32; i += 8)
        out[gbase + (size_t)(c0 + i) * R + r0 + threadIdx.x] = (__bf16)tile[threadIdx.x][i];
}

// ---------------- kv prep: one read of kvin -> kvt (transposed) + kvb (linear) ----------------
__global__ void k_kv_prep(const float* __restrict__ in, __bf16* __restrict__ outT,
                          __bf16* __restrict__ outL) {
    __shared__ float tile[32][33];
    size_t gbase = (size_t)blockIdx.z * S_ * D_;
    int r0 = blockIdx.y * 32, c0 = blockIdx.x * 32;
    #pragma unroll
    for (int i = threadIdx.y; i < 32; i += 8) {
        float v = in[gbase + (size_t)(r0 + i) * D_ + c0 + threadIdx.x];
        tile[i][threadIdx.x] = v;
        outL[gbase + (size_t)(r0 + i) * D_ + c0 + threadIdx.x] = (__bf16)v;
    }
    __syncthreads();
    #pragma unroll
    for (int i = threadIdx.y; i < 32; i += 8)
        outT[gbase + (size_t)(c0 + i) * S_ + r0 + threadIdx.x] = (__bf16)tile[threadIdx.x][i];
}

// ---------------- elementwise f32 -> bf16 ----------------
__global__ void k_cvt(const float* __restrict__ in, __bf16* __restrict__ out, int n8) {
    int i = blockIdx.x * blockDim.x + threadIdx.x;
    if (i >= n8) return;
    const float4* p = (const float4*)(in + (size_t)i * 8);
    float4 f0 = p[0], f1 = p[1];
    __bf16 v[8] = {(__bf16)f0.x, (__bf16)f0.y, (__bf16)f0.z, (__bf16)f0.w,
                   (__bf16)f1.x, (__bf16)f1.y, (__bf16)f1.z, (__bf16)f1.w};
    *(uint4*)(out + (size_t)i * 8) = *(const uint4*)v;
}

// ---------------- Q/K projection: 256^2 8-phase (headsum skeleton) ----------------
// q pre-scaled by (1/sqrt(A)) * log2(e) so fattn uses exp2 directly.
__global__ __launch_bounds__(512) void k_proj(
    const __bf16* __restrict__ qb, const __bf16* __restrict__ kvb,
    const __bf16* __restrict__ wqt, const __bf16* __restrict__ wkt,
    const float* __restrict__ bq, const float* __restrict__ bk,
    __bf16* __restrict__ qp, __bf16* __restrict__ kp) {
    __shared__ __bf16 L[2][4][8192];
    int bid = blockIdx.x;                    // 256 blocks
    int xcd = bid & 7, slot = bid >> 3;      // slot 0..31 = mt
    int which = xcd >> 2;
    int n0 = (xcd & 3) * 256;
    int m0 = slot * 256;
    const __bf16* Ab = (which ? kvb : qb) + (size_t)m0 * D_;
    const __bf16* Bb = (which ? wkt : wqt) + (size_t)n0 * D_;
    const float* bias = which ? bk : bq;
    float scale = which ? 1.0f : 0.18033688011112042f;  // 0.125 * log2(e)
    __bf16* outp = which ? kp : qp;
    int t = threadIdx.x, lane = t & 63, w = t >> 6;
    int wr = w >> 2, wc = w & 3;
    int fr = lane & 15, fg = lane >> 4;
    float bv4[4];
    #pragma unroll
    for (int j = 0; j < 4; ++j)
        bv4[j] = bias[n0 + wc * 64 + j * 16 + fr];
    f32x4 acc[8][4] = {};
    auto stg = [&](int tt, int h, int buf) {
        const __bf16* s = (h < 2) ? (Ab + (size_t)(h * 128) * D_ + tt * 64)
                                  : (Bb + (size_t)((h - 2) * 128) * D_ + tt * 64);
        stage_half(s, D_, &L[buf][h][0], w, lane);
    };
    auto loads = [&](const __bf16* Ah, const __bf16* Bh, int rb0, int mh, int nh,
                     bf16x8 (&af)[4][2], bf16x8 (&bv)[2][2]) {
        #pragma unroll
        for (int i = 0; i < 4; ++i)
            #pragma unroll
            for (int ks = 0; ks < 2; ++ks)
                af[i][ks] = fragS(Ah, mh * 64 + i * 16 + fr, ks, fg);
        #pragma unroll
        for (int j = 0; j < 2; ++j)
            #pragma unroll
            for (int ks = 0; ks < 2; ++ks)
                bv[j][ks] = fragS(Bh, rb0 + nh * 32 + j * 16 + fr, ks, fg);
    };
    stg(0, 0, 0); stg(0, 1, 0); stg(0, 2, 0); stg(0, 3, 0);
    int cur = 0;
    const int nt = D_ / 64;
    for (int tt = 0; tt < nt; ++tt) {
        bool pre = (tt + 1 < nt);
        const __bf16* Ah = &L[cur][wr][0];
        const __bf16* Bh = &L[cur][2 + (wc >> 1)][0];
        int rb0 = (wc & 1) * 64;
        #pragma unroll
        for (int ph = 0; ph < 4; ++ph) {
            const int mh = ph >> 1, nh = ph & 1;
            bf16x8 af[4][2], bv[2][2];
            if (ph == 0) {
                if (pre) {
                    stg(tt + 1, 0, cur ^ 1);
                    stg(tt + 1, 1, cur ^ 1);
                    stg(tt + 1, 2, cur ^ 1);
                    stg(tt + 1, 3, cur ^ 1);
                    asm volatile("s_waitcnt vmcnt(8)" ::: "memory");
                } else {
                    asm volatile("s_waitcnt vmcnt(0)" ::: "memory");
                }
                __builtin_amdgcn_s_barrier();
                __builtin_amdgcn_sched_barrier(0);
                loads(Ah, Bh, rb0, mh, nh, af, bv);
            } else {
                loads(Ah, Bh, rb0, mh, nh, af, bv);
                __builtin_amdgcn_s_barrier();
                __builtin_amdgcn_sched_barrier(0);
            }
            __builtin_amdgcn_s_setprio(1);
            #pragma unroll
            for (int i = 0; i < 4; ++i)
                #pragma unroll
                for (int j = 0; j < 2; ++j) {
                    acc[mh * 4 + i][nh * 2 + j] =
                        mfma16(af[i][0], bv[j][0], acc[mh * 4 + i][nh * 2 + j]);
                    acc[mh * 4 + i][nh * 2 + j] =
                        mfma16(af[i][1], bv[j][1], acc[mh * 4 + i][nh * 2 + j]);
                }
            __builtin_amdgcn_s_setprio(0);
            __builtin_amdgcn_sched_barrier(0);
            __builtin_amdgcn_s_barrier();
        }
        cur ^= 1;
    }
    __bf16* dst = outp + (size_t)m0 * (H_ * A_);
    #pragma unroll
    for (int mi = 0; mi < 8; ++mi)
        #pragma unroll
        for (int jj = 0; jj < 4; ++jj) {
            int mr = wr * 128 + mi * 16 + fg * 4 + jj;
            #pragma unroll
            for (int nj = 0; nj < 4; ++nj) {
                int nc = n0 + wc * 64 + nj * 16 + fr;
                dst[(size_t)mr * (H_ * A_) + nc] =
                    (__bf16)((acc[mi][nj][jj] + bv4[nj]) * scale);
            }
        }
}

// ---------------- fused flash attention, BN=512, XCD-local (R16-exact) ----------------
__global__ __launch_bounds__(512, 1) void k_fattn(
    const __bf16* __restrict__ qpb, const __bf16* __restrict__ kpb,
    const __bf16* __restrict__ kvtb, __bf16* __restrict__ att) {
    __shared__ __bf16 Ks[64 * 64];          // 8 KB, single buffer
    __shared__ __bf16 Vs[2][4][128 * 64];   // 128 KB
    __shared__ __bf16 Ps[128 * 64];         // 16 KB (also Q staging)
    __shared__ float lpar[128][2];          // 1 KB
    int bid = blockIdx.x;                   // 256 blocks
    int xcd = bid & 7, slot = bid >> 3;     // slot 0..31
    int n0 = (xcd & 1) * 512;
    int h = (xcd >> 1) * 4 + (slot >> 3);
    int yp = slot & 7;
    int t = threadIdx.x, lane = t & 63, w = t >> 6;
    int fr = lane & 15, fg = lane >> 4;
    int wr = w >> 2, wc = w & 3;   // PV: rows wr*64, cols wc*128
    int sr = w >> 1, sc = w & 1;   // QK^T: rows sr*32, cols sc*32
    const __bf16* Vb = kvtb + (size_t)n0 * S_;
    __bf16* ob = att + (size_t)h * S_ * D_;
    int kr = w * 8 + (lane >> 3);       // K stage row (64 rows over 8 waves)
    int ksl = SWZ(lane & 7, kr);        // K stage source slot

    #pragma unroll 1
    for (int seg = 0; seg < 2; ++seg) {
        int mt = seg ? (15 - yp) : yp;
        int m0 = mt * 128;
        int NT = (mt + 1) * 2;
        // ---- prologue: Q -> Ps -> regs; K0 glds; V0 glds; K1 -> reg ----
        stage_half(qpb + (size_t)m0 * (H_ * A_) + h * A_, H_ * A_, Ps, w, lane);
        glds16(kpb + (size_t)kr * (H_ * A_) + h * A_ + ksl * 8, Ks + w * 512);
        asm volatile("s_waitcnt vmcnt(0)" ::: "memory");
        __builtin_amdgcn_s_barrier();
        bf16x8 qf[2][2];
        #pragma unroll
        for (int mi = 0; mi < 2; ++mi)
            #pragma unroll
            for (int ks = 0; ks < 2; ++ks)
                qf[mi][ks] = fragS(Ps, sr * 32 + mi * 16 + fr, ks, fg);
        asm volatile("s_waitcnt lgkmcnt(0)" ::: "memory");
        #pragma unroll
        for (int q = 0; q < 4; ++q)
            stage_half(Vb + (size_t)(q * 128) * S_, S_, &Vs[0][q][0], w, lane);
        uint4 kreg = {0, 0, 0, 0};
        if (NT > 1)
            kreg = *(const uint4*)(kpb + (size_t)(64 + kr) * (H_ * A_) + h * A_ + ksl * 8);
        __builtin_amdgcn_s_barrier();  // Q reads done before P~ writes
        __builtin_amdgcn_sched_barrier(0);
        f32x4 acc[4][8] = {};
        float lsum[2][4] = {};
        int cur = 0;
        for (int tt = 0; tt < NT; ++tt) {
            bool pre = (tt + 1 < NT);
            // ---- phase A: wait V(t); issue V(t+1) post-barrier; QK^T + exp + P~ ----
            if (pre) {
                asm volatile("s_waitcnt vmcnt(1)" ::: "memory");   // drain V(t)x8
            } else {
                asm volatile("s_waitcnt vmcnt(0)" ::: "memory");
            }
            asm volatile("s_waitcnt lgkmcnt(0)" ::: "memory");
            __builtin_amdgcn_s_barrier();
            __builtin_amdgcn_sched_barrier(0);
            if (pre) {
                #pragma unroll
                for (int q = 0; q < 4; ++q)
                    stage_half(Vb + (size_t)(q * 128) * S_ + (tt + 1) * 64, S_,
                               &Vs[cur ^ 1][q][0], w, lane);
            }
            f32x4 sac[2][2] = {};
            __builtin_amdgcn_s_setprio(1);
            #pragma unroll
            for (int ks = 0; ks < 2; ++ks)
                #pragma unroll
                for (int nj = 0; nj < 2; ++nj) {
                    bf16x8 kf = fragS(Ks, sc * 32 + nj * 16 + fr, ks, fg);
                    #pragma unroll
                    for (int mi = 0; mi < 2; ++mi)
                        sac[mi][nj] = mfma16(qf[mi][ks], kf, sac[mi][nj]);
                }
            __builtin_amdgcn_s_setprio(0);
            bool dg = (tt >= 2 * mt);   // block-uniform: only last 2 tiles touch diagonal
            if (dg) {
                #pragma unroll
                for (int mi = 0; mi < 2; ++mi)
                    #pragma unroll
                    for (int nj = 0; nj < 2; ++nj)
                        #pragma unroll
                        for (int jj = 0; jj < 4; ++jj) {
                            int srow = sr * 32 + mi * 16 + fg * 4 + jj;
                            int col = sc * 32 + nj * 16 + fr;
                            float p = exp2f(sac[mi][nj][jj]);
                            if (tt * 64 + col > m0 + srow) p = 0.f;
                            lsum[mi][jj] += p;
                            Ps[srow * 64 + (col ^ (fg << 4))] = (__bf16)p;
                        }
            } else {
                #pragma unroll
                for (int mi = 0; mi < 2; ++mi)
                    #pragma unroll
                    for (int nj = 0; nj < 2; ++nj)
                        #pragma unroll
                        for (int jj = 0; jj < 4; ++jj) {
                            int srow = sr * 32 + mi * 16 + fg * 4 + jj;
                            int col = sc * 32 + nj * 16 + fr;
                            float p = exp2f(sac[mi][nj][jj]);
                            lsum[mi][jj] += p;
                            Ps[srow * 64 + (col ^ (fg << 4))] = (__bf16)p;
                        }
            }
            asm volatile("s_waitcnt lgkmcnt(0)" ::: "memory");
            __builtin_amdgcn_s_barrier();
            __builtin_amdgcn_sched_barrier(0);
            // ---- phase B: K(t+1) reg->LDS; PV ----
            if (pre) {
                asm volatile("s_waitcnt vmcnt(8)" ::: "memory");   // drain kreg(t+1)
                *(uint4*)(Ks + w * 512 + lane * 8) = kreg;
                if (tt + 2 < NT)
                    kreg = *(const uint4*)(kpb + (size_t)((tt + 2) * 64 + kr) * (H_ * A_) +
                                           h * A_ + ksl * 8);
            }
            __builtin_amdgcn_s_setprio(1);
            const __bf16* Vh = &Vs[cur][wc][0];
            #pragma unroll
            for (int ks = 0; ks < 2; ++ks) {
                bf16x8 pa[4], vf[8];
                #pragma unroll
                for (int mi = 0; mi < 4; ++mi) {
                    int r = wr * 64 + mi * 16 + fr;
                    int g = (ks * 4 + fg) ^ (((fr >> 2) & 3) << 1);
                    pa[mi] = *(const bf16x8*)(Ps + r * 64 + g * 8);
                }
                #pragma unroll
                for (int nj = 0; nj < 8; ++nj)
                    vf[nj] = fragS(Vh, nj * 16 + fr, ks, fg);
                #pragma unroll
                for (int mi = 0; mi < 4; ++mi)
                    #pragma unroll
                    for (int nj = 0; nj < 8; ++nj)
                        acc[mi][nj] = mfma16(pa[mi], vf[nj], acc[mi][nj]);
            }
            __builtin_amdgcn_s_setprio(0);
            __builtin_amdgcn_sched_barrier(0);
            cur ^= 1;
        }
        // ---- row sums: shfl over fr, combine the 2 col-waves via LDS ----
        #pragma unroll
        for (int mi = 0; mi < 2; ++mi)
            #pragma unroll
            for (int jj = 0; jj < 4; ++jj) {
                float v = lsum[mi][jj];
                v += __shfl_xor(v, 1);
                v += __shfl_xor(v, 2);
                v += __shfl_xor(v, 4);
                v += __shfl_xor(v, 8);
                if (fr == 0) lpar[sr * 32 + mi * 16 + fg * 4 + jj][sc] = v;
            }
        asm volatile("s_waitcnt lgkmcnt(0)" ::: "memory");
        __builtin_amdgcn_s_barrier();
        // ---- epilogue: normalize + store ----
        #pragma unroll
        for (int mi = 0; mi < 4; ++mi)
            #pragma unroll
            for (int jj = 0; jj < 4; ++jj) {
                int row = wr * 64 + mi * 16 + fg * 4 + jj;
                float il = 1.f / (lpar[row][0] + lpar[row][1]);
                int m = m0 + row;
                #pragma unroll
                for (int nj = 0; nj < 8; ++nj) {
                    int n = n0 + wc * 128 + nj * 16 + fr;
                    ob[(size_t)m * D_ + n] = (__bf16)(acc[mi][nj][jj] * il);
                }
            }
        __builtin_amdgcn_s_barrier();  // Ps/lpar/Ks reuse across segs
    }
}

// ---------------- per-head Wo GEMM + bias + relu -> bf16 partials, 256^2 8-phase ----------------
// Partials stored interleaved: asum[row][head][D] so k_ln reads contiguously.
__global__ __launch_bounds__(512) void k_headsum(
    const __bf16* __restrict__ att, const __bf16* __restrict__ Wot,
    const float* __restrict__ bo, __bf16* __restrict__ asum) {
    __shared__ __bf16 L[2][4][8192];
    int bid = blockIdx.x;                    // 512 blocks
    int xcd = bid & 7, slot = bid >> 3;      // slot 0..63
    int p = xcd * 2 + (slot >> 5);           // head 0..15
    int rem = slot & 31;
    int mt = rem >> 2;                       // 0..7
    int n0 = (rem & 3) * 256;
    int m0 = mt * 256;
    int t = threadIdx.x, lane = t & 63, w = t >> 6;
    int wr = w >> 2, wc = w & 3;
    int fr = lane & 15, fg = lane >> 4;
    const __bf16* Ab = att + ((size_t)p * S_ + m0) * D_;
    const __bf16* Bb = Wot + ((size_t)p * D_ + n0) * D_;
    float bv4[4];
    #pragma unroll
    for (int j = 0; j < 4; ++j)
        bv4[j] = bo[(size_t)p * D_ + n0 + wc * 64 + j * 16 + fr];
    f32x4 acc[8][4] = {};
    auto stg = [&](int tt, int h, int buf) {
        const __bf16* s = (h < 2) ? (Ab + (size_t)(h * 128) * D_ + tt * 64)
                                  : (Bb + (size_t)((h - 2) * 128) * D_ + tt * 64);
        stage_half(s, D_, &L[buf][h][0], w, lane);
    };
    auto loads = [&](const __bf16* Ah, const __bf16* Bh, int rb0, int mh, int nh,
                     bf16x8 (&af)[4][2], bf16x8 (&bv)[2][2]) {
        #pragma unroll
        for (int i = 0; i < 4; ++i)
            #pragma unroll
            for (int ks = 0; ks < 2; ++ks)
                af[i][ks] = fragS(Ah, mh * 64 + i * 16 + fr, ks, fg);
        #pragma unroll
        for (int j = 0; j < 2; ++j)
            #pragma unroll
            for (int ks = 0; ks < 2; ++ks)
                bv[j][ks] = fragS(Bh, rb0 + nh * 32 + j * 16 + fr, ks, fg);
    };
    stg(0, 0, 0); stg(0, 1, 0); stg(0, 2, 0); stg(0, 3, 0);
    int cur = 0;
    const int nt = D_ / 64;
    for (int tt = 0; tt < nt; ++tt) {
        bool pre = (tt + 1 < nt);
        const __bf16* Ah = &L[cur][wr][0];
        const __bf16* Bh = &L[cur][2 + (wc >> 1)][0];
        int rb0 = (wc & 1) * 64;
        #pragma unroll
        for (int ph = 0; ph < 4; ++ph) {
            const int mh = ph >> 1, nh = ph & 1;
            bf16x8 af[4][2], bv[2][2];
            if (ph == 0) {
                if (pre) {
                    stg(tt + 1, 0, cur ^ 1);
                    stg(tt + 1, 1, cur ^ 1);
                    stg(tt + 1, 2, cur ^ 1);
                    stg(tt + 1, 3, cur ^ 1);
                    asm volatile("s_waitcnt vmcnt(8)" ::: "memory");
                } else {
                    asm volatile("s_waitcnt vmcnt(0)" ::: "memory");
                }
                __builtin_amdgcn_s_barrier();
                __builtin_amdgcn_sched_barrier(0);
                loads(Ah, Bh, rb0, mh, nh, af, bv);
            } else {
                loads(Ah, Bh, rb0, mh, nh, af, bv);
                __builtin_amdgcn_s_barrier();
                __builtin_amdgcn_sched_barrier(0);
            }
            __builtin_amdgcn_s_setprio(1);
            #pragma unroll
            for (int i = 0; i < 4; ++i)
                #pragma unroll
                for (int j = 0; j < 2; ++j) {
                    acc[mh * 4 + i][nh * 2 + j] =
                        mfma16(af[i][0], bv[j][0], acc[mh * 4 + i][nh * 2 + j]);
                    acc[mh * 4 + i][nh * 2 + j] =
                        mfma16(af[i][1], bv[j][1], acc[mh * 4 + i][nh * 2 + j]);
                }
            __builtin_amdgcn_s_setprio(0);
            __builtin_amdgcn_sched_barrier(0);
            __builtin_amdgcn_s_barrier();
        }
        cur ^= 1;
    }
    #pragma unroll
    for (int mi = 0; mi < 8; ++mi)
        #pragma unroll
        for (int jj = 0; jj < 4; ++jj) {
            int mr = m0 + wr * 128 + mi * 16 + fg * 4 + jj;
            #pragma unroll
            for (int nj = 0; nj < 4; ++nj) {
                int nc = n0 + wc * 64 + nj * 16 + fr;
                asum[((size_t)mr * H_ + p) * D_ + nc] =
                    (__bf16)fmaxf(acc[mi][nj][jj] + bv4[nj], 0.f);
            }
        }
}

// ---------------- residual + 16-partial bf16 sum (interleaved) + LayerNorm ----------------
__global__ __launch_bounds__(256) void k_ln(
    const float* __restrict__ x1b, const __bf16* __restrict__ parts,
    const float* __restrict__ gamma, const float* __restrict__ beta,
    float* __restrict__ outb) {
    int row = blockIdx.x;
    size_t base = (size_t)row * D_;
    int c = threadIdx.x * 4;
    float4 a = *(const float4*)(x1b + base + c);
    float x[4] = {a.x, a.y, a.z, a.w};
    const __bf16* pr = parts + (size_t)row * H_ * D_ + c;
    #pragma unroll
    for (int p = 0; p < H_; ++p) {
        bf16x4 v = *(const bf16x4*)(pr + (size_t)p * D_);
        x[0] += (float)v[0]; x[1] += (float)v[1];
        x[2] += (float)v[2]; x[3] += (float)v[3];
    }
    float sm = x[0] + x[1] + x[2] + x[3];
    float s2 = x[0] * x[0] + x[1] * x[1] + x[2] * x[2] + x[3] * x[3];
    #pragma unroll
    for (int m = 32; m >= 1; m >>= 1) {
        sm += __shfl_xor(sm, m);
        s2 += __shfl_xor(s2, m);
    }
    __shared__ float r1[4], r2[4];
    int w = threadIdx.x >> 6;
    if ((threadIdx.x & 63) == 0) { r1[w] = sm; r2[w] = s2; }
    __syncthreads();
    sm = r1[0] + r1[1] + r1[2] + r1[3];
    s2 = r2[0] + r2[1] + r2[2] + r2[3];
    float mean = sm * (1.f / D_);
    float var = s2 * (1.f / D_) - mean * mean;
    float rstd = rsqrtf(var + LN_EPS);
    #pragma unroll
    for (int jj = 0; jj < 4; ++jj)
        outb[base + c + jj] = gamma[c + jj] * (x[jj] - mean) * rstd + beta[c + jj];
}

// ---------------- host ----------------
extern "C" void kernel_launch(void* const* d_in, const int* in_sizes, int n_in,
                              void* d_out, int out_size, void* d_ws, size_t ws_size,
                              hipStream_t stream) {
    (void)in_sizes; (void)n_in; (void)out_size; (void)ws_size;
    const float* qin   = (const float*)d_in[0];
    const float* kvin  = (const float*)d_in[1];
    const float* Wq    = (const float*)d_in[2];
    const float* bq    = (const float*)d_in[3];
    const float* Wk    = (const float*)d_in[4];
    const float* bk    = (const float*)d_in[5];
    const float* Wo    = (const float*)d_in[6];
    const float* bo    = (const float*)d_in[7];
    const float* gamma = (const float*)d_in[8];
    const float* beta  = (const float*)d_in[9];
    float* out = (float*)d_out;
    char* ws = (char*)d_ws;

    size_t off = 0;
    auto alloc = [&](size_t bytes) {
        size_t o = off;
        off += (bytes + 255) & ~(size_t)255;
        return o;
    };
    size_t o_wqt = alloc((size_t)H_ * A_ * D_ * 2);
    size_t o_wkt = alloc((size_t)H_ * A_ * D_ * 2);
    size_t o_wot = alloc((size_t)H_ * D_ * D_ * 2);
    size_t o_kvt = alloc((size_t)B_ * D_ * S_ * 2);
    size_t o_qp  = alloc((size_t)B_ * S_ * H_ * A_ * 2);
    size_t o_kp  = alloc((size_t)B_ * S_ * H_ * A_ * 2);
    size_t o_att = alloc((size_t)H_ * S_ * D_ * 2);
    // region X: qb+kvb (proj inputs) then asum (bf16 partials) — disjoint lifetimes
    size_t xbytes_qb = (size_t)B_ * S_ * D_ * 2 * 2;
    size_t xbytes_as = (size_t)H_ * S_ * D_ * 2;
    size_t o_x = alloc(xbytes_qb > xbytes_as ? xbytes_qb : xbytes_as);

    __bf16* wqt = (__bf16*)(ws + o_wqt);
    __bf16* wkt = (__bf16*)(ws + o_wkt);
    __bf16* wot = (__bf16*)(ws + o_wot);
    __bf16* kvt = (__bf16*)(ws + o_kvt);
    __bf16* qp  = (__bf16*)(ws + o_qp);
    __bf16* kp  = (__bf16*)(ws + o_kp);
    __bf16* att = (__bf16*)(ws + o_att);
    __bf16* qb  = (__bf16*)(ws + o_x);
    __bf16* kvb = qb + (size_t)B_ * S_ * D_;
    __bf16* asum = (__bf16*)(ws + o_x);

    k_tr_cvt2<<<dim3(A_ / 32, D_ / 32, 2 * H_), dim3(32, 8), 0, stream>>>(
        Wq, Wk, wqt, wkt, D_, A_);
    k_tr_cvt<<<dim3(D_ / 32, D_ / 32, H_), dim3(32, 8), 0, stream>>>(Wo, wot, D_, D_);
    // kv: one read -> transposed kvt + linear kvb
    k_kv_prep<<<dim3(D_ / 32, S_ / 32, B_), dim3(32, 8), 0, stream>>>(kvin, kvt, kvb);
    int n8 = B_ * S_ * D_ / 8;
    k_cvt<<<(n8 + 255) / 256, 256, 0, stream>>>(qin, qb, n8);
    k_proj<<<256, 512, 0, stream>>>(qb, kvb, wqt, wkt, bq, bk, qp, kp);

    for (int b = 0; b < B_; ++b) {
        const __bf16* qpb  = qp + (size_t)b * S_ * (H_ * A_);
        const __bf16* kpb  = kp + (size_t)b * S_ * (H_ * A_);
        const __bf16* kvtb = kvt + (size_t)b * D_ * S_;
        k_fattn<<<256, 512, 0, stream>>>(qpb, kpb, kvtb, att);
        k_headsum<<<512, 512, 0, stream>>>(att, wot, bo, asum);
        k_ln<<<S_, 256, 0, stream>>>(qin + (size_t)b * S_ * D_, asum, gamma, beta,
                                     out + (size_t)b * S_ * D_);
    }
}